// Round 1
// baseline (792.480 us; speedup 1.0000x reference)
//
#include <hip/hip_runtime.h>
#include <math.h>

#define FRAME_LENF 400
#define HOPF 160
#define NFFT 512
#define NBINS 257
#define NMEL 80
#define NFRAMES 2998
#define BATCH 32
#define NSAMP 480000
#define ROWS 1500
#define COLS 160
#define GF 4   // frames per block in k_frames
#define PI_F 3.14159265358979323846f

// ---------------- Kernel 1: frames -> FFT -> power -> mel -> log feats ----------------
__global__ __launch_bounds__(256) void k_frames(
    const float* __restrict__ raw, const float* __restrict__ mask,
    const float* __restrict__ fil, const float* __restrict__ win,
    float* __restrict__ feats)
{
    __shared__ float s_x[FRAME_LENF];
    __shared__ float s_re[NFFT];
    __shared__ float s_im[NFFT];
    __shared__ float s_twr[NFFT / 2];
    __shared__ float s_twi[NFFT / 2];
    __shared__ float s_pow[GF][NBINS];
    __shared__ float s_red[8];

    const int tid = threadIdx.x;
    const int b = blockIdx.y;
    const int fr0 = blockIdx.x * GF;

    // twiddle table: tw[j] = exp(-2*pi*i*j/512), j = 0..255
    {
        float ang = -2.0f * PI_F * (float)tid / (float)NFFT;
        float sv, cv;
        sincosf(ang, &sv, &cv);
        s_twr[tid] = cv;
        s_twi[tid] = sv;
    }

    for (int g = 0; g < GF; ++g) {
        const int fr = fr0 + g;          // block-uniform
        if (fr >= NFRAMES) break;        // uniform branch

        __syncthreads();  // protect s_red / s_re / s_x reuse from previous iteration

        const float* x  = raw  + (size_t)b * NSAMP + (size_t)fr * HOPF;
        const float* mk = mask + (size_t)b * NSAMP + (size_t)fr * HOPF;

        // zero FFT buffers
        s_re[tid] = 0.f; s_re[tid + 256] = 0.f;
        s_im[tid] = 0.f; s_im[tid + 256] = 0.f;

        // load frame (scaled), accumulate partial sum for mean
        float part = 0.f;
        if (tid < FRAME_LENF) {
            float v = x[tid] * 32768.f;
            s_x[tid] = v;
            part += v;
        }
        {
            int i = tid + 256;
            if (i < FRAME_LENF) {
                float v = x[i] * 32768.f;
                s_x[i] = v;
                part += v;
            }
        }
        // wave + block reduce for mean
        for (int o = 32; o > 0; o >>= 1) part += __shfl_down(part, o, 64);
        if ((tid & 63) == 0) s_red[tid >> 6] = part;
        __syncthreads();
        if (tid == 0) s_red[4] = s_red[0] + s_red[1] + s_red[2] + s_red[3];
        __syncthreads();
        const float mean = s_red[4] * (1.0f / (float)FRAME_LENF);

        // pre-emphasis + window + mask, scatter bit-reversed into FFT buffer
        for (int rep = 0; rep < 2; ++rep) {
            int i = tid + rep * 256;
            if (i < FRAME_LENF) {
                float xm = s_x[i] - mean;
                float y;
                if (i == 0) {
                    y = xm * (1.0f - 0.97f);
                } else {
                    float xp = s_x[i - 1] - mean;
                    y = xm - 0.97f * xp;
                }
                y *= win[i] * mk[i];
                int rev = (int)(__brev((unsigned)i) >> 23);
                s_re[rev] = y;
            }
        }
        __syncthreads();

        // radix-2 DIT FFT, 9 stages, 256 butterflies/stage (1 per thread)
        int half = 1, twstep = 256;
        #pragma unroll
        for (int s = 0; s < 9; ++s) {
            int j  = tid & (half - 1);
            int i0 = ((tid ^ j) << 1) | j;
            int i1 = i0 + half;
            int ti = j * twstep;
            float wr = s_twr[ti], wi = s_twi[ti];
            float ur = s_re[i0], ui = s_im[i0];
            float vr = s_re[i1], vi = s_im[i1];
            float tr = vr * wr - vi * wi;
            float tc = vr * wi + vi * wr;
            s_re[i0] = ur + tr; s_im[i0] = ui + tc;
            s_re[i1] = ur - tr; s_im[i1] = ui - tc;
            half <<= 1; twstep >>= 1;
            __syncthreads();
        }

        // power spectrum bins 0..256
        for (int k = tid; k < NBINS; k += 256) {
            float rr = s_re[k], ii = s_im[k];
            s_pow[g][k] = rr * rr + ii * ii;
        }
    }
    __syncthreads();

    // mel projection + log for all frames of this block
    for (int w = tid; w < NMEL * GF; w += 256) {
        int m = w % NMEL;
        int g = w / NMEL;
        int fr = fr0 + g;
        if (fr >= NFRAMES) continue;
        float acc = 0.f;
        #pragma unroll 4
        for (int f = 0; f < NBINS; ++f) {
            acc += s_pow[g][f] * fil[f * NMEL + m];
        }
        feats[((size_t)b * NFRAMES + fr) * NMEL + m] =
            logf(fmaxf(acc, 1.192092955078125e-07f));
    }
}

// ---------------- Kernel 2: per (b, mel) mean / rstd over frames ----------------
__global__ __launch_bounds__(64) void k_stats(const float* __restrict__ feats,
                                              float* __restrict__ mean_out,
                                              float* __restrict__ rstd_out)
{
    const int bm = blockIdx.x;          // 0..2559
    const int b = bm / NMEL, m = bm % NMEL;
    const float* p = feats + (size_t)b * NFRAMES * NMEL + m;
    const int tid = threadIdx.x;
    float s = 0.f, s2 = 0.f;
    for (int fr = tid; fr < NFRAMES; fr += 64) {
        float v = p[(size_t)fr * NMEL];
        s += v; s2 += v * v;
    }
    for (int o = 32; o > 0; o >>= 1) {
        s  += __shfl_down(s, o, 64);
        s2 += __shfl_down(s2, o, 64);
    }
    if (tid == 0) {
        float mean = s / (float)NFRAMES;
        float var = (s2 - s * s / (float)NFRAMES) / (float)(NFRAMES - 1);
        mean_out[bm] = mean;
        rstd_out[bm] = rsqrtf(var + 1e-7f);
    }
}

// ---------------- Kernel 3: normalize + reshape + pad + mask ----------------
__global__ __launch_bounds__(256) void k_out(const float* __restrict__ feats,
                                             const float* __restrict__ meanv,
                                             const float* __restrict__ rstdv,
                                             float* __restrict__ out)
{
    const int totf4 = BATCH * ROWS * COLS / 4;   // 1,920,000
    const int totm  = BATCH * ROWS;              // 48,000
    const int idx = blockIdx.x * blockDim.x + threadIdx.x;
    const int stride = gridDim.x * blockDim.x;

    for (int i = idx; i < totf4; i += stride) {
        int e = i * 4;
        int b  = e / (ROWS * COLS);
        int rc = e % (ROWS * COLS);
        int r = rc / COLS, c = rc % COLS;
        float4 o;
        if (r == ROWS - 1) {
            o = make_float4(1.f, 1.f, 1.f, 1.f);   // padding_value
        } else {
            int fr = 2 * r + (c >= NMEL);
            int m  = c % NMEL;                      // 4-aligned, stays in one half
            const float4 f  = *(const float4*)(feats + ((size_t)b * NFRAMES + fr) * NMEL + m);
            const float4 mu = *(const float4*)(meanv + b * NMEL + m);
            const float4 rs = *(const float4*)(rstdv + b * NMEL + m);
            o.x = (f.x - mu.x) * rs.x;
            o.y = (f.y - mu.y) * rs.y;
            o.z = (f.z - mu.z) * rs.z;
            o.w = (f.w - mu.w) * rs.w;
        }
        *(float4*)(out + e) = o;
    }

    float* omask = out + (size_t)BATCH * ROWS * COLS;
    for (int i = idx; i < totm; i += stride) {
        int r = i % ROWS;
        omask[i] = (r == ROWS - 1) ? 0.0f : 1.0f;
    }
}

extern "C" void kernel_launch(void* const* d_in, const int* in_sizes, int n_in,
                              void* d_out, int out_size, void* d_ws, size_t ws_size,
                              hipStream_t stream)
{
    const float* raw  = (const float*)d_in[0];
    const float* mask = (const float*)d_in[1];
    const float* fil  = (const float*)d_in[2];
    const float* win  = (const float*)d_in[3];
    float* out = (float*)d_out;

    float* feats = (float*)d_ws;                                   // 32*2998*80 floats
    float* meanv = feats + (size_t)BATCH * NFRAMES * NMEL;
    float* rstdv = meanv + BATCH * NMEL;

    dim3 g1((NFRAMES + GF - 1) / GF, BATCH);
    k_frames<<<g1, 256, 0, stream>>>(raw, mask, fil, win, feats);

    k_stats<<<BATCH * NMEL, 64, 0, stream>>>(feats, meanv, rstdv);

    k_out<<<2048, 256, 0, stream>>>(feats, meanv, rstdv, out);
}

// Round 2
// 562.460 us; speedup vs baseline: 1.4090x; 1.4090x over previous
//
#include <hip/hip_runtime.h>
#include <math.h>

#define NFRAMES 2998
#define BATCH 32
#define NSAMP 480000
#define NMEL 80
#define NBINS 257
#define ROWS 1500
#define COLS 160
#define MEL_FLOOR 1.192092955078125e-07f
#define PI_F 3.14159265358979323846f

// XOR bank swizzle for 256-entry FFT rows (valid for a in [0,256))
#define SW(a) ((a) ^ ((a) >> 5))

// ---------- radix-4 Stockham pass (one wave owns one 256-pt FFT) ----------
template<int NS>
__device__ inline void r4pass(const float* __restrict__ sre, const float* __restrict__ sim,
                              float* __restrict__ dre, float* __restrict__ dim_, int j)
{
    const int k = j & (NS - 1);
    float ar = sre[SW(j)],       ai = sim[SW(j)];
    float br = sre[SW(j + 64)],  bi = sim[SW(j + 64)];
    float cr = sre[SW(j + 128)], ci = sim[SW(j + 128)];
    float dr = sre[SW(j + 192)], di = sim[SW(j + 192)];

    float t1r, t1i, t2r, t2i, t3r, t3i;
    if (NS == 1) {
        t1r = br; t1i = bi; t2r = cr; t2i = ci; t3r = dr; t3i = di;
    } else {
        // w1 = exp(-i*pi*k/(2*NS)); w2 = w1^2; w3 = w1*w2
        float s1, c1;
        sincosf((-PI_F / (2.0f * (float)NS)) * (float)k, &s1, &c1);
        float c2 = c1 * c1 - s1 * s1, s2 = 2.0f * c1 * s1;
        float c3 = c1 * c2 - s1 * s2, s3 = c1 * s2 + s1 * c2;
        t1r = br * c1 - bi * s1; t1i = br * s1 + bi * c1;
        t2r = cr * c2 - ci * s2; t2i = cr * s2 + ci * c2;
        t3r = dr * c3 - di * s3; t3i = dr * s3 + di * c3;
    }
    float e0r = ar + t2r,  e0i = ai + t2i;     // v0+v2
    float e1r = ar - t2r,  e1i = ai - t2i;     // v0-v2
    float e2r = t1r + t3r, e2i = t1i + t3i;    // v1+v3
    float e3r = t1r - t3r, e3i = t1i - t3i;    // v1-v3
    const int i0 = 4 * j - 3 * k;
    dre[SW(i0)]          = e0r + e2r;  dim_[SW(i0)]          = e0i + e2i;  // y0
    dre[SW(i0 + NS)]     = e1r + e3i;  dim_[SW(i0 + NS)]     = e1i - e3r;  // y1 = e1 - i*e3
    dre[SW(i0 + 2*NS)]   = e0r - e2r;  dim_[SW(i0 + 2*NS)]   = e0i - e2i;  // y2
    dre[SW(i0 + 3*NS)]   = e1r - e3i;  dim_[SW(i0 + 3*NS)]   = e1i + e3r;  // y3 = e1 + i*e3
}

// ---------- setup: per-mel filter support [lo, len] ----------
__global__ void k_ranges(const float* __restrict__ fil,
                         int* __restrict__ rlo, int* __restrict__ rlen)
{
    int m = threadIdx.x;
    if (m >= NMEL) return;
    int lo = -1, hi = -2;
    for (int f = 0; f < NBINS; ++f) {
        float v = fil[f * NMEL + m];
        if (v > 0.f) { if (lo < 0) lo = f; hi = f; }
    }
    rlo[m]  = (lo < 0) ? 0 : lo;
    rlen[m] = hi - lo + 1;   // 0 when empty
}

// ---------- main: frames -> rFFT(512 via 256-pt complex) -> power -> sparse mel -> log ----------
__global__ __launch_bounds__(256) void k_frames(
    const float* __restrict__ raw, const float* __restrict__ mask,
    const float* __restrict__ fil, const float* __restrict__ win,
    const int* __restrict__ rlo, const int* __restrict__ rlen,
    float* __restrict__ feats)
{
    __shared__ float Are[4][256];
    __shared__ float Aim[4][256];
    __shared__ __align__(16) union {
        struct { float x[896]; float mk[896]; } in;          // staging (880 used)
        struct { float re[4][256]; float im[4][256]; } c;    // FFT ping-pong buffer B
    } U;
    __shared__ float s_pow[4][NBINS];

    const int tid  = threadIdx.x;
    const int wv   = tid >> 6;
    const int lane = tid & 63;
    const int b    = blockIdx.y;
    const int fr0  = blockIdx.x * 4;
    const long sbase = (long)b * NSAMP + (long)fr0 * 160;
    const int  valid = NSAMP - fr0 * 160;   // samples available in this window

    // ---- stage 880 samples + mask into LDS (float4, scaled) ----
    for (int i4 = tid; i4 < 220; i4 += 256) {
        float4 xv = make_float4(0.f, 0.f, 0.f, 0.f);
        float4 mv = make_float4(0.f, 0.f, 0.f, 0.f);
        if (i4 * 4 + 4 <= valid) {
            xv = *(const float4*)(raw  + sbase + i4 * 4);
            mv = *(const float4*)(mask + sbase + i4 * 4);
        }
        xv.x *= 32768.f; xv.y *= 32768.f; xv.z *= 32768.f; xv.w *= 32768.f;
        *(float4*)&U.in.x[i4 * 4]  = xv;
        *(float4*)&U.in.mk[i4 * 4] = mv;
    }
    __syncthreads();   // staging visible to all waves

    // ---- per-frame mean (wave wv owns frame wv) ----
    float part = 0.f;
    for (int i = lane; i < 400; i += 64) part += U.in.x[wv * 160 + i];
    #pragma unroll
    for (int o = 1; o < 64; o <<= 1) part += __shfl_xor(part, o, 64);
    const float fmean = part * (1.0f / 400.0f);

    // ---- pack: z[n] = y(2n) + i*y(2n+1), lane handles n = 4l..4l+3 ----
    {
        const int l = lane;
        float ys[8];
        if (l < 50) {   // 8l..8l+7 <= 399
            const float* xp = &U.in.x[wv * 160 + 8 * l];
            const float* mp = &U.in.mk[wv * 160 + 8 * l];
            float4 x0 = *(const float4*)xp,        x1 = *(const float4*)(xp + 4);
            float4 m0 = *(const float4*)mp,        m1 = *(const float4*)(mp + 4);
            float4 w0 = *(const float4*)(win + 8 * l), w1 = *(const float4*)(win + 8 * l + 4);
            float xm1 = (l > 0) ? xp[-1] : 0.f;
            float xs[8] = {x0.x, x0.y, x0.z, x0.w, x1.x, x1.y, x1.z, x1.w};
            float ms[8] = {m0.x, m0.y, m0.z, m0.w, m1.x, m1.y, m1.z, m1.w};
            float wf[8] = {w0.x, w0.y, w0.z, w0.w, w1.x, w1.y, w1.z, w1.w};
            #pragma unroll
            for (int e = 0; e < 8; ++e) {
                float xc = xs[e];
                float xprev = e ? xs[e - 1] : xm1;
                float y = (8 * l + e == 0) ? 0.03f * (xc - fmean)
                                           : (xc - 0.97f * xprev - 0.03f * fmean);
                ys[e] = y * wf[e] * ms[e];
            }
        } else {
            #pragma unroll
            for (int e = 0; e < 8; ++e) ys[e] = 0.f;
        }
        __syncthreads();   // all waves done reading U.in before U.c gets written
        #pragma unroll
        for (int d = 0; d < 4; ++d) {
            Are[wv][SW(4 * l + d)] = ys[2 * d];
            Aim[wv][SW(4 * l + d)] = ys[2 * d + 1];
        }
    }

    // ---- 256-pt complex FFT: 4 radix-4 Stockham passes (wave-private, no barriers) ----
    r4pass<1 >(&Are[wv][0], &Aim[wv][0], &U.c.re[wv][0], &U.c.im[wv][0], lane);
    r4pass<4 >(&U.c.re[wv][0], &U.c.im[wv][0], &Are[wv][0], &Aim[wv][0], lane);
    r4pass<16>(&Are[wv][0], &Aim[wv][0], &U.c.re[wv][0], &U.c.im[wv][0], lane);
    r4pass<64>(&U.c.re[wv][0], &U.c.im[wv][0], &Are[wv][0], &Aim[wv][0], lane);

    // ---- real-split unpack + power: X[k] = E[k] + W512^k * O[k] ----
    #pragma unroll
    for (int q = 0; q < 4; ++q) {
        int k  = lane + 64 * q;
        int a  = k & 255;
        int b2 = (256 - k) & 255;
        float zar = Are[wv][SW(a)],  zai = Aim[wv][SW(a)];
        float zbr = Are[wv][SW(b2)], zbi = Aim[wv][SW(b2)];
        float Er  = 0.5f * (zar + zbr), Ei = 0.5f * (zai - zbi);
        float Or_ = 0.5f * (zai + zbi), Oi = 0.5f * (zbr - zar);
        float sk, ck;
        sincosf((-PI_F / 256.0f) * (float)k, &sk, &ck);   // exp(-2*pi*i*k/512)
        float Xr = Er + ck * Or_ - sk * Oi;
        float Xi = Ei + ck * Oi + sk * Or_;
        s_pow[wv][k] = Xr * Xr + Xi * Xi;
    }
    if (lane == 0) {   // k = 256: X = Zr[0] - Zi[0] exactly
        float zr = Are[wv][SW(0)], zi = Aim[wv][SW(0)];
        float Xr = zr - zi;
        s_pow[wv][256] = Xr * Xr;
    }
    __syncthreads();   // s_pow visible cross-wave

    // ---- sparse mel + log ----
    for (int p = tid; p < 4 * NMEL; p += 256) {
        int g = p / NMEL, m = p - NMEL * g;
        int fr = fr0 + g;
        if (fr >= NFRAMES) continue;
        int lo = rlo[m], len = rlen[m];
        float acc = 0.f;
        for (int i = 0; i < len; ++i) {
            int f = lo + i;
            acc = fmaf(s_pow[g][f], fil[f * NMEL + m], acc);
        }
        feats[((long)b * NFRAMES + fr) * NMEL + m] = logf(fmaxf(acc, MEL_FLOOR));
    }
}

// ---------- per (b, mel) mean / rstd over frames (coalesced) ----------
__global__ __launch_bounds__(256) void k_stats(const float* __restrict__ feats,
                                               float* __restrict__ meanv,
                                               float* __restrict__ rstdv)
{
    __shared__ float ps[240], ps2[240];
    const int b = blockIdx.x, t = threadIdx.x;
    if (t < 240) {
        int g = t / 80, m = t - 80 * g;
        float s = 0.f, s2 = 0.f;
        const float* base = feats + (long)b * NFRAMES * NMEL + m;
        for (int fr = g; fr < NFRAMES; fr += 3) {
            float v = base[(long)fr * NMEL];
            s += v; s2 += v * v;
        }
        ps[t] = s; ps2[t] = s2;
    }
    __syncthreads();
    if (t < 80) {
        float s  = ps[t]  + ps[t + 80]  + ps[t + 160];
        float s2 = ps2[t] + ps2[t + 80] + ps2[t + 160];
        float mean = s * (1.0f / NFRAMES);
        float var  = (s2 - s * s * (1.0f / NFRAMES)) * (1.0f / (NFRAMES - 1));
        meanv[b * NMEL + t] = mean;
        rstdv[b * NMEL + t] = rsqrtf(var + 1e-7f);
    }
}

// ---------- normalize + reshape + pad + mask ----------
__global__ __launch_bounds__(256) void k_out(const float* __restrict__ feats,
                                             const float* __restrict__ meanv,
                                             const float* __restrict__ rstdv,
                                             float* __restrict__ out)
{
    const int totf4 = BATCH * ROWS * COLS / 4;   // 1,920,000
    const int totm  = BATCH * ROWS;              // 48,000
    const int idx = blockIdx.x * blockDim.x + threadIdx.x;
    const int stride = gridDim.x * blockDim.x;

    for (int i = idx; i < totf4; i += stride) {
        int e = i * 4;
        int b  = e / (ROWS * COLS);
        int rc = e % (ROWS * COLS);
        int r = rc / COLS, c = rc % COLS;
        float4 o;
        if (r == ROWS - 1) {
            o = make_float4(1.f, 1.f, 1.f, 1.f);   // padding_value
        } else {
            int fr = 2 * r + (c >= NMEL);
            int m  = c % NMEL;
            const float4 f  = *(const float4*)(feats + ((long)b * NFRAMES + fr) * NMEL + m);
            const float4 mu = *(const float4*)(meanv + b * NMEL + m);
            const float4 rs = *(const float4*)(rstdv + b * NMEL + m);
            o.x = (f.x - mu.x) * rs.x;
            o.y = (f.y - mu.y) * rs.y;
            o.z = (f.z - mu.z) * rs.z;
            o.w = (f.w - mu.w) * rs.w;
        }
        *(float4*)(out + e) = o;
    }

    float* omask = out + (long)BATCH * ROWS * COLS;
    for (int i = idx; i < totm; i += stride) {
        int r = i % ROWS;
        omask[i] = (r == ROWS - 1) ? 0.0f : 1.0f;
    }
}

extern "C" void kernel_launch(void* const* d_in, const int* in_sizes, int n_in,
                              void* d_out, int out_size, void* d_ws, size_t ws_size,
                              hipStream_t stream)
{
    const float* raw  = (const float*)d_in[0];
    const float* mask = (const float*)d_in[1];
    const float* fil  = (const float*)d_in[2];
    const float* win  = (const float*)d_in[3];
    float* out = (float*)d_out;

    float* feats = (float*)d_ws;                                  // 32*2998*80 f32
    float* meanv = feats + (long)BATCH * NFRAMES * NMEL;
    float* rstdv = meanv + BATCH * NMEL;
    int*   rlo   = (int*)(rstdv + BATCH * NMEL);
    int*   rlen  = rlo + NMEL;

    k_ranges<<<1, 128, 0, stream>>>(fil, rlo, rlen);

    dim3 g1((NFRAMES + 3) / 4, BATCH);
    k_frames<<<g1, 256, 0, stream>>>(raw, mask, fil, win, rlo, rlen, feats);

    k_stats<<<BATCH, 256, 0, stream>>>(feats, meanv, rstdv);

    k_out<<<2048, 256, 0, stream>>>(feats, meanv, rstdv, out);
}

// Round 5
// 307.783 us; speedup vs baseline: 2.5748x; 1.8275x over previous
//
#include <hip/hip_runtime.h>
#include <math.h>

#define NFRAMES 2998
#define BATCH 32
#define NSAMP 480000
#define NMEL 80
#define NBINS 257
#define ROWS 1500
#define COLS 160
#define MEL_FLOOR 1.192092955078125e-07f
#define PI_F 3.14159265358979323846f
#define SCHUNKS 32

// XOR bank swizzle for 256-entry FFT rows (valid for a in [0,256))
#define SW(a) ((a) ^ ((a) >> 5))

// ---------- radix-4 Stockham pass (one wave owns one 256-pt FFT) ----------
template<int NS>
__device__ inline void r4pass(const float* __restrict__ sre, const float* __restrict__ sim,
                              float* __restrict__ dre, float* __restrict__ dim_, int j)
{
    const int k = j & (NS - 1);
    float ar = sre[SW(j)],       ai = sim[SW(j)];
    float br = sre[SW(j + 64)],  bi = sim[SW(j + 64)];
    float cr = sre[SW(j + 128)], ci = sim[SW(j + 128)];
    float dr = sre[SW(j + 192)], di = sim[SW(j + 192)];

    float t1r, t1i, t2r, t2i, t3r, t3i;
    if (NS == 1) {
        t1r = br; t1i = bi; t2r = cr; t2i = ci; t3r = dr; t3i = di;
    } else {
        // w1 = exp(-i*pi*k/(2*NS)); w2 = w1^2; w3 = w1*w2
        float s1, c1;
        sincosf((-PI_F / (2.0f * (float)NS)) * (float)k, &s1, &c1);
        float c2 = c1 * c1 - s1 * s1, s2 = 2.0f * c1 * s1;
        float c3 = c1 * c2 - s1 * s2, s3 = c1 * s2 + s1 * c2;
        t1r = br * c1 - bi * s1; t1i = br * s1 + bi * c1;
        t2r = cr * c2 - ci * s2; t2i = cr * s2 + ci * c2;
        t3r = dr * c3 - di * s3; t3i = dr * s3 + di * c3;
    }
    float e0r = ar + t2r,  e0i = ai + t2i;
    float e1r = ar - t2r,  e1i = ai - t2i;
    float e2r = t1r + t3r, e2i = t1i + t3i;
    float e3r = t1r - t3r, e3i = t1i - t3i;
    const int i0 = 4 * j - 3 * k;
    dre[SW(i0)]          = e0r + e2r;  dim_[SW(i0)]          = e0i + e2i;
    dre[SW(i0 + NS)]     = e1r + e3i;  dim_[SW(i0 + NS)]     = e1i - e3r;
    dre[SW(i0 + 2*NS)]   = e0r - e2r;  dim_[SW(i0 + 2*NS)]   = e0i - e2i;
    dre[SW(i0 + 3*NS)]   = e1r - e3i;  dim_[SW(i0 + 3*NS)]   = e1i + e3r;
}

// ---------- setup: per-mel filter support [lo, len] ----------
__global__ void k_ranges(const float* __restrict__ fil,
                         int* __restrict__ rlo, int* __restrict__ rlen)
{
    int m = threadIdx.x;
    if (m >= NMEL) return;
    int lo = -1, hi = -2;
    for (int f = 0; f < NBINS; ++f) {
        float v = fil[f * NMEL + m];
        if (v > 0.f) { if (lo < 0) lo = f; hi = f; }
    }
    rlo[m]  = (lo < 0) ? 0 : lo;
    rlen[m] = hi - lo + 1;   // 0 when empty
}

// ---------- main: frames -> rFFT(512 via 256-pt complex) -> power -> sparse mel -> log ----------
__global__ __launch_bounds__(256) void k_frames(
    const float* __restrict__ raw, const float* __restrict__ mask,
    const float* __restrict__ fil, const float* __restrict__ win,
    const int* __restrict__ rlo, const int* __restrict__ rlen,
    float* __restrict__ feats)
{
    __shared__ float Are[4][256];
    __shared__ float Aim[4][256];
    __shared__ __align__(16) union {
        struct { float x[896]; float mk[896]; } in;          // staging (880 used)
        struct { float re[4][256]; float im[4][256]; } c;    // FFT ping-pong buffer B
    } U;
    __shared__ float s_pow[4][NBINS];

    const int tid  = threadIdx.x;
    const int wv   = tid >> 6;
    const int lane = tid & 63;
    const int b    = blockIdx.y;
    const int fr0  = blockIdx.x * 4;
    const long sbase = (long)b * NSAMP + (long)fr0 * 160;
    const int  valid = NSAMP - fr0 * 160;

    // ---- stage 880 samples + mask into LDS (float4, scaled) ----
    for (int i4 = tid; i4 < 220; i4 += 256) {
        float4 xv = make_float4(0.f, 0.f, 0.f, 0.f);
        float4 mv = make_float4(0.f, 0.f, 0.f, 0.f);
        if (i4 * 4 + 4 <= valid) {
            xv = *(const float4*)(raw  + sbase + i4 * 4);
            mv = *(const float4*)(mask + sbase + i4 * 4);
        }
        xv.x *= 32768.f; xv.y *= 32768.f; xv.z *= 32768.f; xv.w *= 32768.f;
        *(float4*)&U.in.x[i4 * 4]  = xv;
        *(float4*)&U.in.mk[i4 * 4] = mv;
    }
    __syncthreads();

    // ---- per-frame mean (wave wv owns frame wv) ----
    float part = 0.f;
    for (int i = lane; i < 400; i += 64) part += U.in.x[wv * 160 + i];
    #pragma unroll
    for (int o = 1; o < 64; o <<= 1) part += __shfl_xor(part, o, 64);
    const float fmean = part * (1.0f / 400.0f);

    // ---- pack: z[n] = y(2n) + i*y(2n+1), lane handles n = 4l..4l+3 ----
    {
        const int l = lane;
        float ys[8];
        if (l < 50) {
            const float* xp = &U.in.x[wv * 160 + 8 * l];
            const float* mp = &U.in.mk[wv * 160 + 8 * l];
            float4 x0 = *(const float4*)xp,        x1 = *(const float4*)(xp + 4);
            float4 m0 = *(const float4*)mp,        m1 = *(const float4*)(mp + 4);
            float4 w0 = *(const float4*)(win + 8 * l), w1 = *(const float4*)(win + 8 * l + 4);
            float xm1 = (l > 0) ? xp[-1] : 0.f;
            float xs[8] = {x0.x, x0.y, x0.z, x0.w, x1.x, x1.y, x1.z, x1.w};
            float ms[8] = {m0.x, m0.y, m0.z, m0.w, m1.x, m1.y, m1.z, m1.w};
            float wf[8] = {w0.x, w0.y, w0.z, w0.w, w1.x, w1.y, w1.z, w1.w};
            #pragma unroll
            for (int e = 0; e < 8; ++e) {
                float xc = xs[e];
                float xprev = e ? xs[e - 1] : xm1;
                float y = (8 * l + e == 0) ? 0.03f * (xc - fmean)
                                           : (xc - 0.97f * xprev - 0.03f * fmean);
                ys[e] = y * wf[e] * ms[e];
            }
        } else {
            #pragma unroll
            for (int e = 0; e < 8; ++e) ys[e] = 0.f;
        }
        __syncthreads();
        #pragma unroll
        for (int d = 0; d < 4; ++d) {
            Are[wv][SW(4 * l + d)] = ys[2 * d];
            Aim[wv][SW(4 * l + d)] = ys[2 * d + 1];
        }
    }

    // ---- 256-pt complex FFT: 4 radix-4 Stockham passes (wave-private) ----
    r4pass<1 >(&Are[wv][0], &Aim[wv][0], &U.c.re[wv][0], &U.c.im[wv][0], lane);
    r4pass<4 >(&U.c.re[wv][0], &U.c.im[wv][0], &Are[wv][0], &Aim[wv][0], lane);
    r4pass<16>(&Are[wv][0], &Aim[wv][0], &U.c.re[wv][0], &U.c.im[wv][0], lane);
    r4pass<64>(&U.c.re[wv][0], &U.c.im[wv][0], &Are[wv][0], &Aim[wv][0], lane);

    // ---- real-split unpack + power ----
    #pragma unroll
    for (int q = 0; q < 4; ++q) {
        int k  = lane + 64 * q;
        int a  = k & 255;
        int b2 = (256 - k) & 255;
        float zar = Are[wv][SW(a)],  zai = Aim[wv][SW(a)];
        float zbr = Are[wv][SW(b2)], zbi = Aim[wv][SW(b2)];
        float Er  = 0.5f * (zar + zbr), Ei = 0.5f * (zai - zbi);
        float Or_ = 0.5f * (zai + zbi), Oi = 0.5f * (zbr - zar);
        float sk, ck;
        sincosf((-PI_F / 256.0f) * (float)k, &sk, &ck);
        float Xr = Er + ck * Or_ - sk * Oi;
        float Xi = Ei + ck * Oi + sk * Or_;
        s_pow[wv][k] = Xr * Xr + Xi * Xi;
    }
    if (lane == 0) {
        float zr = Are[wv][SW(0)], zi = Aim[wv][SW(0)];
        float Xr = zr - zi;
        s_pow[wv][256] = Xr * Xr;
    }
    __syncthreads();

    // ---- sparse mel + log ----
    for (int p = tid; p < 4 * NMEL; p += 256) {
        int g = p / NMEL, m = p - NMEL * g;
        int fr = fr0 + g;
        if (fr >= NFRAMES) continue;
        int lo = rlo[m], len = rlen[m];
        float acc = 0.f;
        for (int i = 0; i < len; ++i) {
            int f = lo + i;
            acc = fmaf(s_pow[g][f], fil[f * NMEL + m], acc);
        }
        feats[((long)b * NFRAMES + fr) * NMEL + m] = logf(fmaxf(acc, MEL_FLOOR));
    }
}

// ---------- stats stage 1: per (b, chunk) partial sums, coalesced float4 ----------
__global__ __launch_bounds__(256) void k_stats1(const float* __restrict__ feats,
                                                float* __restrict__ partials)
{
    const int b  = blockIdx.x;
    const int ch = blockIdx.y;
    const int t  = threadIdx.x;
    const int fr0 = (NFRAMES * ch) / SCHUNKS;
    const int fr1 = (NFRAMES * (ch + 1)) / SCHUNKS;

    float4 s  = make_float4(0.f, 0.f, 0.f, 0.f);
    float4 s2 = make_float4(0.f, 0.f, 0.f, 0.f);
    if (t < 240) {
        const int c = t % 20;        // float4 column within the 80-float row
        const int r = t / 20;        // 0..11
        const float4* base = (const float4*)(feats + (long)b * NFRAMES * NMEL);
        for (int fr = fr0 + r; fr < fr1; fr += 12) {
            float4 v = base[(long)fr * 20 + c];
            s.x += v.x; s.y += v.y; s.z += v.z; s.w += v.w;
            s2.x += v.x * v.x; s2.y += v.y * v.y; s2.z += v.z * v.z; s2.w += v.w * v.w;
        }
    }
    __shared__ float4 ls[240], ls2[240];
    if (t < 240) { ls[t] = s; ls2[t] = s2; }
    __syncthreads();
    if (t < 20) {
        float4 a = ls[t], a2 = ls2[t];
        for (int r = 1; r < 12; ++r) {
            float4 u = ls[r * 20 + t], u2 = ls2[r * 20 + t];
            a.x += u.x; a.y += u.y; a.z += u.z; a.w += u.w;
            a2.x += u2.x; a2.y += u2.y; a2.z += u2.z; a2.w += u2.w;
        }
        float4* p = (float4*)(partials + (long)(b * SCHUNKS + ch) * 2 * NMEL);
        p[t]      = a;    // floats [4t..4t+3]      = sum
        p[20 + t] = a2;   // floats [80+4t..80+4t+3]= sumsq
    }
}

// ---------- stats stage 2: fold chunks -> mean / rstd ----------
__global__ __launch_bounds__(128) void k_stats2(const float* __restrict__ partials,
                                                float* __restrict__ meanv,
                                                float* __restrict__ rstdv)
{
    const int b = blockIdx.x;
    const int m = threadIdx.x;
    if (m >= NMEL) return;
    float s = 0.f, s2 = 0.f;
    for (int ch = 0; ch < SCHUNKS; ++ch) {
        const float* p = partials + (long)(b * SCHUNKS + ch) * 2 * NMEL;
        s  += p[m];
        s2 += p[NMEL + m];
    }
    float mean = s * (1.0f / NFRAMES);
    float var  = (s2 - s * s * (1.0f / NFRAMES)) * (1.0f / (NFRAMES - 1));
    meanv[b * NMEL + m] = mean;
    rstdv[b * NMEL + m] = rsqrtf(var + 1e-7f);
}

// ---------- normalize + reshape + pad + mask ----------
__global__ __launch_bounds__(256) void k_out(const float* __restrict__ feats,
                                             const float* __restrict__ meanv,
                                             const float* __restrict__ rstdv,
                                             float* __restrict__ out)
{
    const int totf4 = BATCH * ROWS * COLS / 4;   // 1,920,000
    const int totm  = BATCH * ROWS;              // 48,000
    const int idx = blockIdx.x * blockDim.x + threadIdx.x;
    const int stride = gridDim.x * blockDim.x;

    for (int i = idx; i < totf4; i += stride) {
        int e = i * 4;
        int b  = e / (ROWS * COLS);
        int rc = e % (ROWS * COLS);
        int r = rc / COLS, c = rc % COLS;
        float4 o;
        if (r == ROWS - 1) {
            o = make_float4(1.f, 1.f, 1.f, 1.f);   // padding_value
        } else {
            int fr = 2 * r + (c >= NMEL);
            int m  = c % NMEL;
            const float4 f  = *(const float4*)(feats + ((long)b * NFRAMES + fr) * NMEL + m);
            const float4 mu = *(const float4*)(meanv + b * NMEL + m);
            const float4 rs = *(const float4*)(rstdv + b * NMEL + m);
            o.x = (f.x - mu.x) * rs.x;
            o.y = (f.y - mu.y) * rs.y;
            o.z = (f.z - mu.z) * rs.z;
            o.w = (f.w - mu.w) * rs.w;
        }
        *(float4*)(out + e) = o;
    }

    float* omask = out + (long)BATCH * ROWS * COLS;
    for (int i = idx; i < totm; i += stride) {
        int r = i % ROWS;
        omask[i] = (r == ROWS - 1) ? 0.0f : 1.0f;
    }
}

extern "C" void kernel_launch(void* const* d_in, const int* in_sizes, int n_in,
                              void* d_out, int out_size, void* d_ws, size_t ws_size,
                              hipStream_t stream)
{
    const float* raw  = (const float*)d_in[0];
    const float* mask = (const float*)d_in[1];
    const float* fil  = (const float*)d_in[2];
    const float* win  = (const float*)d_in[3];
    float* out = (float*)d_out;

    float* feats    = (float*)d_ws;                               // 32*2998*80 f32
    float* meanv    = feats + (long)BATCH * NFRAMES * NMEL;
    float* rstdv    = meanv + BATCH * NMEL;
    float* partials = rstdv + BATCH * NMEL;                       // 32*32*160 f32
    int*   rlo      = (int*)(partials + (long)BATCH * SCHUNKS * 2 * NMEL);
    int*   rlen     = rlo + NMEL;

    k_ranges<<<1, 128, 0, stream>>>(fil, rlo, rlen);

    dim3 g1((NFRAMES + 3) / 4, BATCH);
    k_frames<<<g1, 256, 0, stream>>>(raw, mask, fil, win, rlo, rlen, feats);

    dim3 gs(BATCH, SCHUNKS);
    k_stats1<<<gs, 256, 0, stream>>>(feats, partials);
    k_stats2<<<BATCH, 128, 0, stream>>>(partials, meanv, rstdv);

    k_out<<<2048, 256, 0, stream>>>(feats, meanv, rstdv, out);
}

// Round 6
// 274.428 us; speedup vs baseline: 2.8878x; 1.1215x over previous
//
#include <hip/hip_runtime.h>
#include <math.h>

#define NFRAMES 2998
#define BATCH 32
#define NSAMP 480000
#define NMEL 80
#define NBINS 257
#define ROWS 1500
#define COLS 160
#define MEL_FLOOR 1.192092955078125e-07f
#define PI_F 3.14159265358979323846f
#define SCHUNKS 32

// XOR bank swizzle for 256-entry FFT rows (valid for a in [0,256))
#define SW(a) ((a) ^ ((a) >> 5))

// ---------- radix-4 Stockham pass (one wave owns one 256-pt FFT) ----------
// All twiddle angles are in (-pi/2, 0] -> __sincosf (hw v_sin/v_cos) is safe.
template<int NS>
__device__ inline void r4pass(const float* __restrict__ sre, const float* __restrict__ sim,
                              float* __restrict__ dre, float* __restrict__ dim_, int j)
{
    const int k = j & (NS - 1);
    float ar = sre[SW(j)],       ai = sim[SW(j)];
    float br = sre[SW(j + 64)],  bi = sim[SW(j + 64)];
    float cr = sre[SW(j + 128)], ci = sim[SW(j + 128)];
    float dr = sre[SW(j + 192)], di = sim[SW(j + 192)];

    float t1r, t1i, t2r, t2i, t3r, t3i;
    if (NS == 1) {
        t1r = br; t1i = bi; t2r = cr; t2i = ci; t3r = dr; t3i = di;
    } else {
        // w1 = exp(-i*pi*k/(2*NS)); w2 = w1^2; w3 = w1*w2
        float s1, c1;
        __sincosf((-PI_F / (2.0f * (float)NS)) * (float)k, &s1, &c1);
        float c2 = c1 * c1 - s1 * s1, s2 = 2.0f * c1 * s1;
        float c3 = c1 * c2 - s1 * s2, s3 = c1 * s2 + s1 * c2;
        t1r = br * c1 - bi * s1; t1i = br * s1 + bi * c1;
        t2r = cr * c2 - ci * s2; t2i = cr * s2 + ci * c2;
        t3r = dr * c3 - di * s3; t3i = dr * s3 + di * c3;
    }
    float e0r = ar + t2r,  e0i = ai + t2i;
    float e1r = ar - t2r,  e1i = ai - t2i;
    float e2r = t1r + t3r, e2i = t1i + t3i;
    float e3r = t1r - t3r, e3i = t1i - t3i;
    const int i0 = 4 * j - 3 * k;
    dre[SW(i0)]          = e0r + e2r;  dim_[SW(i0)]          = e0i + e2i;
    dre[SW(i0 + NS)]     = e1r + e3i;  dim_[SW(i0 + NS)]     = e1i - e3r;
    dre[SW(i0 + 2*NS)]   = e0r - e2r;  dim_[SW(i0 + 2*NS)]   = e0i - e2i;
    dre[SW(i0 + 3*NS)]   = e1r - e3i;  dim_[SW(i0 + 3*NS)]   = e1i + e3r;
}

// ---------- setup: per-mel filter support [lo, len] — one wave per mel ----------
__global__ __launch_bounds__(256) void k_ranges(const float* __restrict__ fil,
                                                int* __restrict__ rlo, int* __restrict__ rlen)
{
    const int m    = blockIdx.x * 4 + (threadIdx.x >> 6);   // 20 blocks x 4 waves = 80 mels
    const int lane = threadIdx.x & 63;
    int lo = NBINS, hi = -1;
    for (int f = lane; f < NBINS; f += 64) {
        if (fil[f * NMEL + m] > 0.f) { lo = min(lo, f); hi = max(hi, f); }
    }
    #pragma unroll
    for (int o = 1; o < 64; o <<= 1) {
        lo = min(lo, __shfl_xor(lo, o, 64));
        hi = max(hi, __shfl_xor(hi, o, 64));
    }
    if (lane == 0) {
        rlo[m]  = (hi < 0) ? 0 : lo;
        rlen[m] = (hi < 0) ? 0 : (hi - lo + 1);
    }
}

// ---------- main: frames -> rFFT(512 via 256-pt complex) -> power -> sparse mel -> log ----------
__global__ __launch_bounds__(256) void k_frames(
    const float* __restrict__ raw, const float* __restrict__ mask,
    const float* __restrict__ fil, const float* __restrict__ win,
    const int* __restrict__ rlo, const int* __restrict__ rlen,
    float* __restrict__ feats)
{
    __shared__ float Are[4][256];
    __shared__ float Aim[4][256];
    __shared__ __align__(16) union {
        struct { float x[896]; float mk[896]; } in;          // staging (880 used)
        struct { float re[4][256]; float im[4][256]; } c;    // FFT ping-pong buffer B
    } U;
    __shared__ float s_pow[4][NBINS];

    const int tid  = threadIdx.x;
    const int wv   = tid >> 6;
    const int lane = tid & 63;
    const int b    = blockIdx.y;
    const int fr0  = blockIdx.x * 4;
    const long sbase = (long)b * NSAMP + (long)fr0 * 160;
    const int  valid = NSAMP - fr0 * 160;

    // ---- stage 880 samples + mask into LDS (float4, scaled) ----
    for (int i4 = tid; i4 < 220; i4 += 256) {
        float4 xv = make_float4(0.f, 0.f, 0.f, 0.f);
        float4 mv = make_float4(0.f, 0.f, 0.f, 0.f);
        if (i4 * 4 + 4 <= valid) {
            xv = *(const float4*)(raw  + sbase + i4 * 4);
            mv = *(const float4*)(mask + sbase + i4 * 4);
        }
        xv.x *= 32768.f; xv.y *= 32768.f; xv.z *= 32768.f; xv.w *= 32768.f;
        *(float4*)&U.in.x[i4 * 4]  = xv;
        *(float4*)&U.in.mk[i4 * 4] = mv;
    }
    __syncthreads();

    // ---- per-frame mean (wave wv owns frame wv) ----
    float part = 0.f;
    for (int i = lane; i < 400; i += 64) part += U.in.x[wv * 160 + i];
    #pragma unroll
    for (int o = 1; o < 64; o <<= 1) part += __shfl_xor(part, o, 64);
    const float fmean = part * (1.0f / 400.0f);

    // ---- pack: z[n] = y(2n) + i*y(2n+1), lane handles n = 4l..4l+3 ----
    {
        const int l = lane;
        float ys[8];
        if (l < 50) {
            const float* xp = &U.in.x[wv * 160 + 8 * l];
            const float* mp = &U.in.mk[wv * 160 + 8 * l];
            float4 x0 = *(const float4*)xp,        x1 = *(const float4*)(xp + 4);
            float4 m0 = *(const float4*)mp,        m1 = *(const float4*)(mp + 4);
            float4 w0 = *(const float4*)(win + 8 * l), w1 = *(const float4*)(win + 8 * l + 4);
            float xm1 = (l > 0) ? xp[-1] : 0.f;
            float xs[8] = {x0.x, x0.y, x0.z, x0.w, x1.x, x1.y, x1.z, x1.w};
            float ms[8] = {m0.x, m0.y, m0.z, m0.w, m1.x, m1.y, m1.z, m1.w};
            float wf[8] = {w0.x, w0.y, w0.z, w0.w, w1.x, w1.y, w1.z, w1.w};
            #pragma unroll
            for (int e = 0; e < 8; ++e) {
                float xc = xs[e];
                float xprev = e ? xs[e - 1] : xm1;
                float y = (8 * l + e == 0) ? 0.03f * (xc - fmean)
                                           : (xc - 0.97f * xprev - 0.03f * fmean);
                ys[e] = y * wf[e] * ms[e];
            }
        } else {
            #pragma unroll
            for (int e = 0; e < 8; ++e) ys[e] = 0.f;
        }
        __syncthreads();
        #pragma unroll
        for (int d = 0; d < 4; ++d) {
            Are[wv][SW(4 * l + d)] = ys[2 * d];
            Aim[wv][SW(4 * l + d)] = ys[2 * d + 1];
        }
    }

    // ---- 256-pt complex FFT: 4 radix-4 Stockham passes (wave-private) ----
    r4pass<1 >(&Are[wv][0], &Aim[wv][0], &U.c.re[wv][0], &U.c.im[wv][0], lane);
    r4pass<4 >(&U.c.re[wv][0], &U.c.im[wv][0], &Are[wv][0], &Aim[wv][0], lane);
    r4pass<16>(&Are[wv][0], &Aim[wv][0], &U.c.re[wv][0], &U.c.im[wv][0], lane);
    r4pass<64>(&U.c.re[wv][0], &U.c.im[wv][0], &Are[wv][0], &Aim[wv][0], lane);

    // ---- real-split unpack + power ----
    #pragma unroll
    for (int q = 0; q < 4; ++q) {
        int k  = lane + 64 * q;
        int a  = k & 255;
        int b2 = (256 - k) & 255;
        float zar = Are[wv][SW(a)],  zai = Aim[wv][SW(a)];
        float zbr = Are[wv][SW(b2)], zbi = Aim[wv][SW(b2)];
        float Er  = 0.5f * (zar + zbr), Ei = 0.5f * (zai - zbi);
        float Or_ = 0.5f * (zai + zbi), Oi = 0.5f * (zbr - zar);
        float sk, ck;
        __sincosf((-PI_F / 256.0f) * (float)k, &sk, &ck);   // angle in (-pi, 0]
        float Xr = Er + ck * Or_ - sk * Oi;
        float Xi = Ei + ck * Oi + sk * Or_;
        s_pow[wv][k] = Xr * Xr + Xi * Xi;
    }
    if (lane == 0) {
        float zr = Are[wv][SW(0)], zi = Aim[wv][SW(0)];
        float Xr = zr - zi;
        s_pow[wv][256] = Xr * Xr;
    }
    __syncthreads();

    // ---- sparse mel + log ----
    for (int p = tid; p < 4 * NMEL; p += 256) {
        int g = p / NMEL, m = p - NMEL * g;
        int fr = fr0 + g;
        if (fr >= NFRAMES) continue;
        int lo = rlo[m], len = rlen[m];
        float acc = 0.f;
        for (int i = 0; i < len; ++i) {
            int f = lo + i;
            acc = fmaf(s_pow[g][f], fil[f * NMEL + m], acc);
        }
        feats[((long)b * NFRAMES + fr) * NMEL + m] = __logf(fmaxf(acc, MEL_FLOOR));
    }
}

// ---------- stats stage 1: per (b, chunk) partial sums, coalesced float4 ----------
__global__ __launch_bounds__(256) void k_stats1(const float* __restrict__ feats,
                                                float* __restrict__ partials)
{
    const int b  = blockIdx.x;
    const int ch = blockIdx.y;
    const int t  = threadIdx.x;
    const int fr0 = (NFRAMES * ch) / SCHUNKS;
    const int fr1 = (NFRAMES * (ch + 1)) / SCHUNKS;

    float4 s  = make_float4(0.f, 0.f, 0.f, 0.f);
    float4 s2 = make_float4(0.f, 0.f, 0.f, 0.f);
    if (t < 240) {
        const int c = t % 20;        // float4 column within the 80-float row
        const int r = t / 20;        // 0..11
        const float4* base = (const float4*)(feats + (long)b * NFRAMES * NMEL);
        for (int fr = fr0 + r; fr < fr1; fr += 12) {
            float4 v = base[(long)fr * 20 + c];
            s.x += v.x; s.y += v.y; s.z += v.z; s.w += v.w;
            s2.x += v.x * v.x; s2.y += v.y * v.y; s2.z += v.z * v.z; s2.w += v.w * v.w;
        }
    }
    __shared__ float4 ls[240], ls2[240];
    if (t < 240) { ls[t] = s; ls2[t] = s2; }
    __syncthreads();
    if (t < 20) {
        float4 a = ls[t], a2 = ls2[t];
        for (int r = 1; r < 12; ++r) {
            float4 u = ls[r * 20 + t], u2 = ls2[r * 20 + t];
            a.x += u.x; a.y += u.y; a.z += u.z; a.w += u.w;
            a2.x += u2.x; a2.y += u2.y; a2.z += u2.z; a2.w += u2.w;
        }
        float4* p = (float4*)(partials + (long)(b * SCHUNKS + ch) * 2 * NMEL);
        p[t]      = a;    // floats [4t..4t+3]      = sum
        p[20 + t] = a2;   // floats [80+4t..80+4t+3]= sumsq
    }
}

// ---------- stats stage 2: fold chunks -> mean / rstd ----------
__global__ __launch_bounds__(128) void k_stats2(const float* __restrict__ partials,
                                                float* __restrict__ meanv,
                                                float* __restrict__ rstdv)
{
    const int b = blockIdx.x;
    const int m = threadIdx.x;
    if (m >= NMEL) return;
    float s = 0.f, s2 = 0.f;
    for (int ch = 0; ch < SCHUNKS; ++ch) {
        const float* p = partials + (long)(b * SCHUNKS + ch) * 2 * NMEL;
        s  += p[m];
        s2 += p[NMEL + m];
    }
    float mean = s * (1.0f / NFRAMES);
    float var  = (s2 - s * s * (1.0f / NFRAMES)) * (1.0f / (NFRAMES - 1));
    meanv[b * NMEL + m] = mean;
    rstdv[b * NMEL + m] = rsqrtf(var + 1e-7f);
}

// ---------- normalize + reshape + pad + mask ----------
__global__ __launch_bounds__(256) void k_out(const float* __restrict__ feats,
                                             const float* __restrict__ meanv,
                                             const float* __restrict__ rstdv,
                                             float* __restrict__ out)
{
    const int totf4 = BATCH * ROWS * COLS / 4;   // 1,920,000
    const int totm  = BATCH * ROWS;              // 48,000
    const int idx = blockIdx.x * blockDim.x + threadIdx.x;
    const int stride = gridDim.x * blockDim.x;

    for (int i = idx; i < totf4; i += stride) {
        int e = i * 4;
        int b  = e / (ROWS * COLS);
        int rc = e % (ROWS * COLS);
        int r = rc / COLS, c = rc % COLS;
        float4 o;
        if (r == ROWS - 1) {
            o = make_float4(1.f, 1.f, 1.f, 1.f);   // padding_value
        } else {
            int fr = 2 * r + (c >= NMEL);
            int m  = c % NMEL;
            const float4 f  = *(const float4*)(feats + ((long)b * NFRAMES + fr) * NMEL + m);
            const float4 mu = *(const float4*)(meanv + b * NMEL + m);
            const float4 rs = *(const float4*)(rstdv + b * NMEL + m);
            o.x = (f.x - mu.x) * rs.x;
            o.y = (f.y - mu.y) * rs.y;
            o.z = (f.z - mu.z) * rs.z;
            o.w = (f.w - mu.w) * rs.w;
        }
        *(float4*)(out + e) = o;
    }

    float* omask = out + (long)BATCH * ROWS * COLS;
    for (int i = idx; i < totm; i += stride) {
        int r = i % ROWS;
        omask[i] = (r == ROWS - 1) ? 0.0f : 1.0f;
    }
}

extern "C" void kernel_launch(void* const* d_in, const int* in_sizes, int n_in,
                              void* d_out, int out_size, void* d_ws, size_t ws_size,
                              hipStream_t stream)
{
    const float* raw  = (const float*)d_in[0];
    const float* mask = (const float*)d_in[1];
    const float* fil  = (const float*)d_in[2];
    const float* win  = (const float*)d_in[3];
    float* out = (float*)d_out;

    float* feats    = (float*)d_ws;                               // 32*2998*80 f32
    float* meanv    = feats + (long)BATCH * NFRAMES * NMEL;
    float* rstdv    = meanv + BATCH * NMEL;
    float* partials = rstdv + BATCH * NMEL;                       // 32*32*160 f32
    int*   rlo      = (int*)(partials + (long)BATCH * SCHUNKS * 2 * NMEL);
    int*   rlen     = rlo + NMEL;

    k_ranges<<<20, 256, 0, stream>>>(fil, rlo, rlen);

    dim3 g1((NFRAMES + 3) / 4, BATCH);
    k_frames<<<g1, 256, 0, stream>>>(raw, mask, fil, win, rlo, rlen, feats);

    dim3 gs(BATCH, SCHUNKS);
    k_stats1<<<gs, 256, 0, stream>>>(feats, partials);
    k_stats2<<<BATCH, 128, 0, stream>>>(partials, meanv, rstdv);

    k_out<<<2048, 256, 0, stream>>>(feats, meanv, rstdv, out);
}

// Round 7
// 273.329 us; speedup vs baseline: 2.8994x; 1.0040x over previous
//
#include <hip/hip_runtime.h>
#include <math.h>

#define NFRAMES 2998
#define BATCH 32
#define NSAMP 480000
#define NMEL 80
#define NBINS 257
#define ROWS 1500
#define COLS 160
#define MEL_FLOOR 1.192092955078125e-07f
#define PI_F 3.14159265358979323846f
#define SCHUNKS 32

// XOR bank swizzle for 256-entry float2 FFT rows.
// bank(e) = 2e mod 32; SW2 injects (e>>4)&3 into BOTH bit-pairs of e&15,
// making all Stockham read/write patterns (NS=1,4,16,64) conflict-free.
#define SW2(a) ((a) ^ (5 * (((a) >> 4) & 3)))

// ---------- radix-4 Stockham pass on float2 LDS (one wave owns one 256-pt FFT) ----------
// All twiddle angles are in (-pi/2, 0] -> __sincosf (hw v_sin/v_cos) is safe.
template<int NS>
__device__ inline void r4pass2(const float2* __restrict__ s, float2* __restrict__ d, int j)
{
    const int k = j & (NS - 1);
    float2 va = s[SW2(j)];
    float2 vb = s[SW2(j + 64)];
    float2 vc = s[SW2(j + 128)];
    float2 vd = s[SW2(j + 192)];

    float t1r, t1i, t2r, t2i, t3r, t3i;
    if (NS == 1) {
        t1r = vb.x; t1i = vb.y; t2r = vc.x; t2i = vc.y; t3r = vd.x; t3i = vd.y;
    } else {
        // w1 = exp(-i*pi*k/(2*NS)); w2 = w1^2; w3 = w1*w2
        float s1, c1;
        __sincosf((-PI_F / (2.0f * (float)NS)) * (float)k, &s1, &c1);
        float c2 = c1 * c1 - s1 * s1, s2 = 2.0f * c1 * s1;
        float c3 = c1 * c2 - s1 * s2, s3 = c1 * s2 + s1 * c2;
        t1r = vb.x * c1 - vb.y * s1; t1i = vb.x * s1 + vb.y * c1;
        t2r = vc.x * c2 - vc.y * s2; t2i = vc.x * s2 + vc.y * c2;
        t3r = vd.x * c3 - vd.y * s3; t3i = vd.x * s3 + vd.y * c3;
    }
    float e0r = va.x + t2r, e0i = va.y + t2i;
    float e1r = va.x - t2r, e1i = va.y - t2i;
    float e2r = t1r + t3r,  e2i = t1i + t3i;
    float e3r = t1r - t3r,  e3i = t1i - t3i;
    const int i0 = 4 * j - 3 * k;
    d[SW2(i0)]          = make_float2(e0r + e2r, e0i + e2i);
    d[SW2(i0 + NS)]     = make_float2(e1r + e3i, e1i - e3r);   // e1 - i*e3
    d[SW2(i0 + 2*NS)]   = make_float2(e0r - e2r, e0i - e2i);
    d[SW2(i0 + 3*NS)]   = make_float2(e1r - e3i, e1i + e3r);   // e1 + i*e3
}

// ---------- setup: per-mel filter support [lo, len] — one wave per mel ----------
__global__ __launch_bounds__(256) void k_ranges(const float* __restrict__ fil,
                                                int* __restrict__ rlo, int* __restrict__ rlen)
{
    const int m    = blockIdx.x * 4 + (threadIdx.x >> 6);   // 20 blocks x 4 waves = 80 mels
    const int lane = threadIdx.x & 63;
    int lo = NBINS, hi = -1;
    for (int f = lane; f < NBINS; f += 64) {
        if (fil[f * NMEL + m] > 0.f) { lo = min(lo, f); hi = max(hi, f); }
    }
    #pragma unroll
    for (int o = 1; o < 64; o <<= 1) {
        lo = min(lo, __shfl_xor(lo, o, 64));
        hi = max(hi, __shfl_xor(hi, o, 64));
    }
    if (lane == 0) {
        rlo[m]  = (hi < 0) ? 0 : lo;
        rlen[m] = (hi < 0) ? 0 : (hi - lo + 1);
    }
}

// ---------- main: frames -> rFFT(512 via 256-pt complex) -> power -> sparse mel -> log ----------
__global__ __launch_bounds__(256) void k_frames(
    const float* __restrict__ raw, const float* __restrict__ mask,
    const float* __restrict__ fil, const float* __restrict__ win,
    const int* __restrict__ rlo, const int* __restrict__ rlen,
    float* __restrict__ feats)
{
    __shared__ float2 A2[4][256];                            // FFT buffer A (8 KB)
    __shared__ __align__(16) union {
        struct { float x[896]; float mk[896]; } in;          // staging (880 used)
        float2 c2[4][256];                                   // FFT ping-pong buffer B
    } U;
    __shared__ float s_pow[4][NBINS];

    const int tid  = threadIdx.x;
    const int wv   = tid >> 6;
    const int lane = tid & 63;
    const int b    = blockIdx.y;
    const int fr0  = blockIdx.x * 4;
    const long sbase = (long)b * NSAMP + (long)fr0 * 160;
    const int  valid = NSAMP - fr0 * 160;

    // ---- stage 880 samples + mask into LDS (float4, scaled) ----
    for (int i4 = tid; i4 < 220; i4 += 256) {
        float4 xv = make_float4(0.f, 0.f, 0.f, 0.f);
        float4 mv = make_float4(0.f, 0.f, 0.f, 0.f);
        if (i4 * 4 + 4 <= valid) {
            xv = *(const float4*)(raw  + sbase + i4 * 4);
            mv = *(const float4*)(mask + sbase + i4 * 4);
        }
        xv.x *= 32768.f; xv.y *= 32768.f; xv.z *= 32768.f; xv.w *= 32768.f;
        *(float4*)&U.in.x[i4 * 4]  = xv;
        *(float4*)&U.in.mk[i4 * 4] = mv;
    }
    __syncthreads();

    // ---- per-frame mean (wave wv owns frame wv) ----
    float part = 0.f;
    for (int i = lane; i < 400; i += 64) part += U.in.x[wv * 160 + i];
    #pragma unroll
    for (int o = 1; o < 64; o <<= 1) part += __shfl_xor(part, o, 64);
    const float fmean = part * (1.0f / 400.0f);

    // ---- pack: z[n] = y(2n) + i*y(2n+1), lane handles n = 4l..4l+3 ----
    {
        const int l = lane;
        float ys[8];
        if (l < 50) {
            const float* xp = &U.in.x[wv * 160 + 8 * l];
            const float* mp = &U.in.mk[wv * 160 + 8 * l];
            float4 x0 = *(const float4*)xp,        x1 = *(const float4*)(xp + 4);
            float4 m0 = *(const float4*)mp,        m1 = *(const float4*)(mp + 4);
            float4 w0 = *(const float4*)(win + 8 * l), w1 = *(const float4*)(win + 8 * l + 4);
            float xm1 = (l > 0) ? xp[-1] : 0.f;
            float xs[8] = {x0.x, x0.y, x0.z, x0.w, x1.x, x1.y, x1.z, x1.w};
            float ms[8] = {m0.x, m0.y, m0.z, m0.w, m1.x, m1.y, m1.z, m1.w};
            float wf[8] = {w0.x, w0.y, w0.z, w0.w, w1.x, w1.y, w1.z, w1.w};
            #pragma unroll
            for (int e = 0; e < 8; ++e) {
                float xc = xs[e];
                float xprev = e ? xs[e - 1] : xm1;
                float y = (8 * l + e == 0) ? 0.03f * (xc - fmean)
                                           : (xc - 0.97f * xprev - 0.03f * fmean);
                ys[e] = y * wf[e] * ms[e];
            }
        } else {
            #pragma unroll
            for (int e = 0; e < 8; ++e) ys[e] = 0.f;
        }
        __syncthreads();   // all waves done reading U.in before U.c2 gets written (pass 1)
        #pragma unroll
        for (int d = 0; d < 4; ++d) {
            A2[wv][SW2(4 * l + d)] = make_float2(ys[2 * d], ys[2 * d + 1]);
        }
    }

    // ---- 256-pt complex FFT: 4 radix-4 Stockham passes (wave-private) ----
    r4pass2<1 >(&A2[wv][0],   &U.c2[wv][0], lane);
    r4pass2<4 >(&U.c2[wv][0], &A2[wv][0],   lane);
    r4pass2<16>(&A2[wv][0],   &U.c2[wv][0], lane);
    r4pass2<64>(&U.c2[wv][0], &A2[wv][0],   lane);

    // ---- real-split unpack + power ----
    #pragma unroll
    for (int q = 0; q < 4; ++q) {
        int k  = lane + 64 * q;
        int a  = k & 255;
        int b2 = (256 - k) & 255;
        float2 za = A2[wv][SW2(a)];
        float2 zb = A2[wv][SW2(b2)];
        float Er  = 0.5f * (za.x + zb.x), Ei = 0.5f * (za.y - zb.y);
        float Or_ = 0.5f * (za.y + zb.y), Oi = 0.5f * (zb.x - za.x);
        float sk, ck;
        __sincosf((-PI_F / 256.0f) * (float)k, &sk, &ck);   // angle in (-pi, 0]
        float Xr = Er + ck * Or_ - sk * Oi;
        float Xi = Ei + ck * Oi + sk * Or_;
        s_pow[wv][k] = Xr * Xr + Xi * Xi;
    }
    if (lane == 0) {
        float2 z0 = A2[wv][SW2(0)];
        float Xr = z0.x - z0.y;
        s_pow[wv][256] = Xr * Xr;
    }
    __syncthreads();

    // ---- sparse mel + log ----
    for (int p = tid; p < 4 * NMEL; p += 256) {
        int g = p / NMEL, m = p - NMEL * g;
        int fr = fr0 + g;
        if (fr >= NFRAMES) continue;
        int lo = rlo[m], len = rlen[m];
        float acc = 0.f;
        for (int i = 0; i < len; ++i) {
            int f = lo + i;
            acc = fmaf(s_pow[g][f], fil[f * NMEL + m], acc);
        }
        feats[((long)b * NFRAMES + fr) * NMEL + m] = __logf(fmaxf(acc, MEL_FLOOR));
    }
}

// ---------- stats stage 1: per (b, chunk) partial sums, coalesced float4 ----------
__global__ __launch_bounds__(256) void k_stats1(const float* __restrict__ feats,
                                                float* __restrict__ partials)
{
    const int b  = blockIdx.x;
    const int ch = blockIdx.y;
    const int t  = threadIdx.x;
    const int fr0 = (NFRAMES * ch) / SCHUNKS;
    const int fr1 = (NFRAMES * (ch + 1)) / SCHUNKS;

    float4 s  = make_float4(0.f, 0.f, 0.f, 0.f);
    float4 s2 = make_float4(0.f, 0.f, 0.f, 0.f);
    if (t < 240) {
        const int c = t % 20;        // float4 column within the 80-float row
        const int r = t / 20;        // 0..11
        const float4* base = (const float4*)(feats + (long)b * NFRAMES * NMEL);
        for (int fr = fr0 + r; fr < fr1; fr += 12) {
            float4 v = base[(long)fr * 20 + c];
            s.x += v.x; s.y += v.y; s.z += v.z; s.w += v.w;
            s2.x += v.x * v.x; s2.y += v.y * v.y; s2.z += v.z * v.z; s2.w += v.w * v.w;
        }
    }
    __shared__ float4 ls[240], ls2[240];
    if (t < 240) { ls[t] = s; ls2[t] = s2; }
    __syncthreads();
    if (t < 20) {
        float4 a = ls[t], a2 = ls2[t];
        for (int r = 1; r < 12; ++r) {
            float4 u = ls[r * 20 + t], u2 = ls2[r * 20 + t];
            a.x += u.x; a.y += u.y; a.z += u.z; a.w += u.w;
            a2.x += u2.x; a2.y += u2.y; a2.z += u2.z; a2.w += u2.w;
        }
        float4* p = (float4*)(partials + (long)(b * SCHUNKS + ch) * 2 * NMEL);
        p[t]      = a;    // floats [0..79]   = sum
        p[20 + t] = a2;   // floats [80..159] = sumsq
    }
}

// ---------- fused: fold chunks -> mean/rstd (prologue) + normalize + pad + mask ----------
__global__ __launch_bounds__(256) void k_out(const float* __restrict__ feats,
                                             const float* __restrict__ partials,
                                             float* __restrict__ out)
{
    const int b = blockIdx.y;
    const int t = threadIdx.x;
    __shared__ float sm[NMEL], sr[NMEL];

    if (t < NMEL) {
        const float* p = partials + (long)b * SCHUNKS * 2 * NMEL;
        float s = 0.f, s2 = 0.f;
        #pragma unroll 4
        for (int ch = 0; ch < SCHUNKS; ++ch) {
            s  += p[ch * 2 * NMEL + t];
            s2 += p[ch * 2 * NMEL + NMEL + t];
        }
        float mean = s * (1.0f / NFRAMES);
        float var  = (s2 - s * s * (1.0f / NFRAMES)) * (1.0f / (NFRAMES - 1));
        sm[t] = mean;
        sr[t] = rsqrtf(var + 1e-7f);
    }
    __syncthreads();

    const int tot4 = ROWS * COLS / 4;   // 60000 float4 per batch
    float* ob = out + (long)b * ROWS * COLS;
    for (int i = blockIdx.x * 256 + t; i < tot4; i += gridDim.x * 256) {
        int e = i * 4;
        int r = e / COLS, c = e % COLS;
        float4 o;
        if (r == ROWS - 1) {
            o = make_float4(1.f, 1.f, 1.f, 1.f);   // padding_value
        } else {
            int fr = 2 * r + (c >= NMEL);
            int m  = c % NMEL;                      // 4-aligned, stays in one half
            const float4 f = *(const float4*)(feats + ((long)b * NFRAMES + fr) * NMEL + m);
            o.x = (f.x - sm[m])     * sr[m];
            o.y = (f.y - sm[m + 1]) * sr[m + 1];
            o.z = (f.z - sm[m + 2]) * sr[m + 2];
            o.w = (f.w - sm[m + 3]) * sr[m + 3];
        }
        *(float4*)(ob + e) = o;
    }

    if (blockIdx.x == 0) {
        float* omask = out + (long)BATCH * ROWS * COLS + (long)b * ROWS;
        for (int i = t; i < ROWS; i += 256) {
            omask[i] = (i == ROWS - 1) ? 0.0f : 1.0f;
        }
    }
}

extern "C" void kernel_launch(void* const* d_in, const int* in_sizes, int n_in,
                              void* d_out, int out_size, void* d_ws, size_t ws_size,
                              hipStream_t stream)
{
    const float* raw  = (const float*)d_in[0];
    const float* mask = (const float*)d_in[1];
    const float* fil  = (const float*)d_in[2];
    const float* win  = (const float*)d_in[3];
    float* out = (float*)d_out;

    float* feats    = (float*)d_ws;                               // 32*2998*80 f32
    float* partials = feats + (long)BATCH * NFRAMES * NMEL;       // 32*32*160 f32
    int*   rlo      = (int*)(partials + (long)BATCH * SCHUNKS * 2 * NMEL);
    int*   rlen     = rlo + NMEL;

    k_ranges<<<20, 256, 0, stream>>>(fil, rlo, rlen);

    dim3 g1((NFRAMES + 3) / 4, BATCH);
    k_frames<<<g1, 256, 0, stream>>>(raw, mask, fil, win, rlo, rlen, feats);

    dim3 gs(BATCH, SCHUNKS);
    k_stats1<<<gs, 256, 0, stream>>>(feats, partials);

    dim3 go(16, BATCH);
    k_out<<<go, 256, 0, stream>>>(feats, partials, out);
}

// Round 11
// 249.207 us; speedup vs baseline: 3.1800x; 1.0968x over previous
//
#include <hip/hip_runtime.h>
#include <math.h>

#define NFRAMES 2998
#define BATCH 32
#define NSAMP 480000
#define NMEL 80
#define NBINS 257
#define ROWS 1500
#define COLS 160
#define MEL_FLOOR 1.192092955078125e-07f
#define PI_F 3.14159265358979323846f
#define SCHUNKS 32
#define MAXW 20          // max mel-triangle width in bins (true max ~18)

// XOR bank swizzle for 256-entry float2 FFT rows.
#define SW2(a) ((a) ^ (5 * (((a) >> 4) & 3)))

// ---------- radix-4 Stockham pass on float2 LDS (one wave owns one 256-pt FFT) ----------
template<int NS>
__device__ inline void r4pass2(const float2* __restrict__ s, float2* __restrict__ d, int j)
{
    const int k = j & (NS - 1);
    float2 va = s[SW2(j)];
    float2 vb = s[SW2(j + 64)];
    float2 vc = s[SW2(j + 128)];
    float2 vd = s[SW2(j + 192)];

    float t1r, t1i, t2r, t2i, t3r, t3i;
    if (NS == 1) {
        t1r = vb.x; t1i = vb.y; t2r = vc.x; t2i = vc.y; t3r = vd.x; t3i = vd.y;
    } else {
        float s1, c1;
        __sincosf((-PI_F / (2.0f * (float)NS)) * (float)k, &s1, &c1);
        float c2 = c1 * c1 - s1 * s1, s2 = 2.0f * c1 * s1;
        float c3 = c1 * c2 - s1 * s2, s3 = c1 * s2 + s1 * c2;
        t1r = vb.x * c1 - vb.y * s1; t1i = vb.x * s1 + vb.y * c1;
        t2r = vc.x * c2 - vc.y * s2; t2i = vc.x * s2 + vc.y * c2;
        t3r = vd.x * c3 - vd.y * s3; t3i = vd.x * s3 + vd.y * c3;
    }
    float e0r = va.x + t2r, e0i = va.y + t2i;
    float e1r = va.x - t2r, e1i = va.y - t2i;
    float e2r = t1r + t3r,  e2i = t1i + t3i;
    float e3r = t1r - t3r,  e3i = t1i - t3i;
    const int i0 = 4 * j - 3 * k;
    d[SW2(i0)]          = make_float2(e0r + e2r, e0i + e2i);
    d[SW2(i0 + NS)]     = make_float2(e1r + e3i, e1i - e3r);
    d[SW2(i0 + 2*NS)]   = make_float2(e0r - e2r, e0i - e2i);
    d[SW2(i0 + 3*NS)]   = make_float2(e1r - e3i, e1i + e3r);
}

// ---------- setup: per-mel support + dense padded filter table filT[MAXW][80] ----------
__global__ __launch_bounds__(256) void k_ranges(const float* __restrict__ fil,
                                                int* __restrict__ rlo,
                                                float* __restrict__ filT)
{
    const int m    = blockIdx.x * 4 + (threadIdx.x >> 6);   // 20 blocks x 4 waves = 80 mels
    const int lane = threadIdx.x & 63;
    int lo = NBINS, hi = -1;
    for (int f = lane; f < NBINS; f += 64) {
        if (fil[f * NMEL + m] > 0.f) { lo = min(lo, f); hi = max(hi, f); }
    }
    #pragma unroll
    for (int o = 1; o < 64; o <<= 1) {
        lo = min(lo, __shfl_xor(lo, o, 64));
        hi = max(hi, __shfl_xor(hi, o, 64));
    }
    if (hi < 0) { lo = 0; hi = -1; }          // empty filter -> all zeros
    if (lane == 0) rlo[m] = lo;
    // fill padded dense column: filT[i][m], i in [0, MAXW)
    if (lane < MAXW) {
        int f = lo + lane;
        float v = (f <= hi && f < NBINS) ? fil[f * NMEL + m] : 0.f;
        filT[lane * NMEL + m] = v;
    }
}

// ---------- main: frames -> rFFT(512 via 256-pt complex) -> power -> dense-padded mel -> log ----------
__global__ __launch_bounds__(256) void k_frames(
    const float* __restrict__ raw, const float* __restrict__ mask,
    const float* __restrict__ filT, const float* __restrict__ win,
    const int* __restrict__ rlo,
    float* __restrict__ feats)
{
    __shared__ float2 A2[4][256];                            // FFT buffer A (8 KB)
    __shared__ __align__(16) union {
        struct { float x[896]; float mk[896]; } in;          // staging (880 used)
        float2 c2[4][256];                                   // FFT ping-pong buffer B
    } U;
    __shared__ float s_pow[4][280];                          // 257 bins + zero pad
    __shared__ float s_filT[MAXW * NMEL];                    // 6.4 KB
    __shared__ int   s_rlo[NMEL];

    const int tid  = threadIdx.x;
    const int wv   = tid >> 6;
    const int lane = tid & 63;
    const int b    = blockIdx.y;
    const int fr0  = blockIdx.x * 4;
    const long sbase = (long)b * NSAMP + (long)fr0 * 160;
    const int  valid = NSAMP - fr0 * 160;

    // ---- stage filter table + rlo (L2-resident, coalesced) ----
    for (int i4 = tid; i4 < MAXW * NMEL / 4; i4 += 256) {
        *(float4*)&s_filT[i4 * 4] = *(const float4*)&filT[i4 * 4];
    }
    if (tid < NMEL) s_rlo[tid] = rlo[tid];

    // ---- stage 880 samples + mask into LDS (float4, scaled) ----
    for (int i4 = tid; i4 < 220; i4 += 256) {
        float4 xv = make_float4(0.f, 0.f, 0.f, 0.f);
        float4 mv = make_float4(0.f, 0.f, 0.f, 0.f);
        if (i4 * 4 + 4 <= valid) {
            xv = *(const float4*)(raw  + sbase + i4 * 4);
            mv = *(const float4*)(mask + sbase + i4 * 4);
        }
        xv.x *= 32768.f; xv.y *= 32768.f; xv.z *= 32768.f; xv.w *= 32768.f;
        *(float4*)&U.in.x[i4 * 4]  = xv;
        *(float4*)&U.in.mk[i4 * 4] = mv;
    }
    __syncthreads();

    // ---- per-frame mean (wave wv owns frame wv) ----
    float part = 0.f;
    for (int i = lane; i < 400; i += 64) part += U.in.x[wv * 160 + i];
    #pragma unroll
    for (int o = 1; o < 64; o <<= 1) part += __shfl_xor(part, o, 64);
    const float fmean = part * (1.0f / 400.0f);

    // ---- pack: z[n] = y(2n) + i*y(2n+1), lane handles n = 4l..4l+3 ----
    {
        const int l = lane;
        float ys[8];
        if (l < 50) {
            const float* xp = &U.in.x[wv * 160 + 8 * l];
            const float* mp = &U.in.mk[wv * 160 + 8 * l];
            float4 x0 = *(const float4*)xp,        x1 = *(const float4*)(xp + 4);
            float4 m0 = *(const float4*)mp,        m1 = *(const float4*)(mp + 4);
            float4 w0 = *(const float4*)(win + 8 * l), w1 = *(const float4*)(win + 8 * l + 4);
            float xm1 = (l > 0) ? xp[-1] : 0.f;
            float xs[8] = {x0.x, x0.y, x0.z, x0.w, x1.x, x1.y, x1.z, x1.w};
            float ms[8] = {m0.x, m0.y, m0.z, m0.w, m1.x, m1.y, m1.z, m1.w};
            float wf[8] = {w0.x, w0.y, w0.z, w0.w, w1.x, w1.y, w1.z, w1.w};
            #pragma unroll
            for (int e = 0; e < 8; ++e) {
                float xc = xs[e];
                float xprev = e ? xs[e - 1] : xm1;
                float y = (8 * l + e == 0) ? 0.03f * (xc - fmean)
                                           : (xc - 0.97f * xprev - 0.03f * fmean);
                ys[e] = y * wf[e] * ms[e];
            }
        } else {
            #pragma unroll
            for (int e = 0; e < 8; ++e) ys[e] = 0.f;
        }
        __syncthreads();   // all waves done reading U.in before U.c2 gets written (pass 1)
        #pragma unroll
        for (int d = 0; d < 4; ++d) {
            A2[wv][SW2(4 * l + d)] = make_float2(ys[2 * d], ys[2 * d + 1]);
        }
    }

    // ---- 256-pt complex FFT: 4 radix-4 Stockham passes (wave-private) ----
    r4pass2<1 >(&A2[wv][0],   &U.c2[wv][0], lane);
    r4pass2<4 >(&U.c2[wv][0], &A2[wv][0],   lane);
    r4pass2<16>(&A2[wv][0],   &U.c2[wv][0], lane);
    r4pass2<64>(&U.c2[wv][0], &A2[wv][0],   lane);

    // ---- real-split unpack + power ----
    #pragma unroll
    for (int q = 0; q < 4; ++q) {
        int k  = lane + 64 * q;
        int a  = k & 255;
        int b2 = (256 - k) & 255;
        float2 za = A2[wv][SW2(a)];
        float2 zb = A2[wv][SW2(b2)];
        float Er  = 0.5f * (za.x + zb.x), Ei = 0.5f * (za.y - zb.y);
        float Or_ = 0.5f * (za.y + zb.y), Oi = 0.5f * (zb.x - za.x);
        float sk, ck;
        __sincosf((-PI_F / 256.0f) * (float)k, &sk, &ck);
        float Xr = Er + ck * Or_ - sk * Oi;
        float Xi = Ei + ck * Oi + sk * Or_;
        s_pow[wv][k] = Xr * Xr + Xi * Xi;
    }
    if (lane == 0) {
        float2 z0 = A2[wv][SW2(0)];
        float Xr = z0.x - z0.y;
        s_pow[wv][256] = Xr * Xr;
    }
    if (lane < 23) s_pow[wv][257 + lane] = 0.f;   // zero pad so lo+MAXW-1 stays clean
    __syncthreads();

    // ---- dense padded mel (fixed MAXW iters, all-LDS) + log ----
    for (int p = tid; p < 4 * NMEL; p += 256) {
        int g = p / NMEL, m = p - NMEL * g;
        int fr = fr0 + g;
        if (fr >= NFRAMES) continue;
        int lo = s_rlo[m];
        float acc = 0.f;
        #pragma unroll
        for (int i = 0; i < MAXW; ++i) {
            acc = fmaf(s_pow[g][lo + i], s_filT[i * NMEL + m], acc);
        }
        feats[((long)b * NFRAMES + fr) * NMEL + m] = __logf(fmaxf(acc, MEL_FLOOR));
    }
}

// ---------- stats stage 1: per (b, chunk) partial sums, coalesced float4 ----------
__global__ __launch_bounds__(256) void k_stats1(const float* __restrict__ feats,
                                                float* __restrict__ partials)
{
    const int b  = blockIdx.x;
    const int ch = blockIdx.y;
    const int t  = threadIdx.x;
    const int fr0 = (NFRAMES * ch) / SCHUNKS;
    const int fr1 = (NFRAMES * (ch + 1)) / SCHUNKS;

    float4 s  = make_float4(0.f, 0.f, 0.f, 0.f);
    float4 s2 = make_float4(0.f, 0.f, 0.f, 0.f);
    if (t < 240) {
        const int c = t % 20;
        const int r = t / 20;
        const float4* base = (const float4*)(feats + (long)b * NFRAMES * NMEL);
        for (int fr = fr0 + r; fr < fr1; fr += 12) {
            float4 v = base[(long)fr * 20 + c];
            s.x += v.x; s.y += v.y; s.z += v.z; s.w += v.w;
            s2.x += v.x * v.x; s2.y += v.y * v.y; s2.z += v.z * v.z; s2.w += v.w * v.w;
        }
    }
    __shared__ float4 ls[240], ls2[240];
    if (t < 240) { ls[t] = s; ls2[t] = s2; }
    __syncthreads();
    if (t < 20) {
        float4 a = ls[t], a2 = ls2[t];
        for (int r = 1; r < 12; ++r) {
            float4 u = ls[r * 20 + t], u2 = ls2[r * 20 + t];
            a.x += u.x; a.y += u.y; a.z += u.z; a.w += u.w;
            a2.x += u2.x; a2.y += u2.y; a2.z += u2.z; a2.w += u2.w;
        }
        float4* p = (float4*)(partials + (long)(b * SCHUNKS + ch) * 2 * NMEL);
        p[t]      = a;
        p[20 + t] = a2;
    }
}

// ---------- fused: fold chunks -> mean/rstd (prologue) + normalize + pad + mask ----------
__global__ __launch_bounds__(256) void k_out(const float* __restrict__ feats,
                                             const float* __restrict__ partials,
                                             float* __restrict__ out)
{
    const int b = blockIdx.y;
    const int t = threadIdx.x;
    __shared__ float sm[NMEL], sr[NMEL];

    if (t < NMEL) {
        const float* p = partials + (long)b * SCHUNKS * 2 * NMEL;
        float s = 0.f, s2 = 0.f;
        #pragma unroll 4
        for (int ch = 0; ch < SCHUNKS; ++ch) {
            s  += p[ch * 2 * NMEL + t];
            s2 += p[ch * 2 * NMEL + NMEL + t];
        }
        float mean = s * (1.0f / NFRAMES);
        float var  = (s2 - s * s * (1.0f / NFRAMES)) * (1.0f / (NFRAMES - 1));
        sm[t] = mean;
        sr[t] = rsqrtf(var + 1e-7f);
    }
    __syncthreads();

    const int tot4 = ROWS * COLS / 4;
    float* ob = out + (long)b * ROWS * COLS;
    for (int i = blockIdx.x * 256 + t; i < tot4; i += gridDim.x * 256) {
        int e = i * 4;
        int r = e / COLS, c = e % COLS;
        float4 o;
        if (r == ROWS - 1) {
            o = make_float4(1.f, 1.f, 1.f, 1.f);
        } else {
            int fr = 2 * r + (c >= NMEL);
            int m  = c % NMEL;
            const float4 f = *(const float4*)(feats + ((long)b * NFRAMES + fr) * NMEL + m);
            o.x = (f.x - sm[m])     * sr[m];
            o.y = (f.y - sm[m + 1]) * sr[m + 1];
            o.z = (f.z - sm[m + 2]) * sr[m + 2];
            o.w = (f.w - sm[m + 3]) * sr[m + 3];
        }
        *(float4*)(ob + e) = o;
    }

    if (blockIdx.x == 0) {
        float* omask = out + (long)BATCH * ROWS * COLS + (long)b * ROWS;
        for (int i = t; i < ROWS; i += 256) {
            omask[i] = (i == ROWS - 1) ? 0.0f : 1.0f;
        }
    }
}

extern "C" void kernel_launch(void* const* d_in, const int* in_sizes, int n_in,
                              void* d_out, int out_size, void* d_ws, size_t ws_size,
                              hipStream_t stream)
{
    const float* raw  = (const float*)d_in[0];
    const float* mask = (const float*)d_in[1];
    const float* fil  = (const float*)d_in[2];
    const float* win  = (const float*)d_in[3];
    float* out = (float*)d_out;

    float* feats    = (float*)d_ws;                               // 32*2998*80 f32
    float* partials = feats + (long)BATCH * NFRAMES * NMEL;       // 32*32*160 f32
    float* filT     = partials + (long)BATCH * SCHUNKS * 2 * NMEL;// 20*80 f32
    int*   rlo      = (int*)(filT + MAXW * NMEL);                 // 80 i32

    k_ranges<<<20, 256, 0, stream>>>(fil, rlo, filT);

    dim3 g1((NFRAMES + 3) / 4, BATCH);
    k_frames<<<g1, 256, 0, stream>>>(raw, mask, filT, win, rlo, feats);

    dim3 gs(BATCH, SCHUNKS);
    k_stats1<<<gs, 256, 0, stream>>>(feats, partials);

    dim3 go(16, BATCH);
    k_out<<<go, 256, 0, stream>>>(feats, partials, out);
}

// Round 12
// 242.636 us; speedup vs baseline: 3.2661x; 1.0271x over previous
//
#include <hip/hip_runtime.h>
#include <math.h>

#define NFRAMES 2998
#define BATCH 32
#define NSAMP 480000
#define NMEL 80
#define NBINS 257
#define ROWS 1500
#define COLS 160
#define MEL_FLOOR 1.192092955078125e-07f
#define PI_F 3.14159265358979323846f
#define SCHUNKS 32
#define MAXW 20          // max mel-triangle width in bins (true max ~18)

// XOR bank swizzle for 256-entry float2 FFT rows.
#define SW2(a) ((a) ^ (5 * (((a) >> 4) & 3)))

// ---------- radix-4 Stockham pass on float2 LDS (one wave owns one 256-pt FFT) ----------
template<int NS>
__device__ inline void r4pass2(const float2* __restrict__ s, float2* __restrict__ d, int j)
{
    const int k = j & (NS - 1);
    float2 va = s[SW2(j)];
    float2 vb = s[SW2(j + 64)];
    float2 vc = s[SW2(j + 128)];
    float2 vd = s[SW2(j + 192)];

    float t1r, t1i, t2r, t2i, t3r, t3i;
    if (NS == 1) {
        t1r = vb.x; t1i = vb.y; t2r = vc.x; t2i = vc.y; t3r = vd.x; t3i = vd.y;
    } else {
        float s1, c1;
        __sincosf((-PI_F / (2.0f * (float)NS)) * (float)k, &s1, &c1);
        float c2 = c1 * c1 - s1 * s1, s2 = 2.0f * c1 * s1;
        float c3 = c1 * c2 - s1 * s2, s3 = c1 * s2 + s1 * c2;
        t1r = vb.x * c1 - vb.y * s1; t1i = vb.x * s1 + vb.y * c1;
        t2r = vc.x * c2 - vc.y * s2; t2i = vc.x * s2 + vc.y * c2;
        t3r = vd.x * c3 - vd.y * s3; t3i = vd.x * s3 + vd.y * c3;
    }
    float e0r = va.x + t2r, e0i = va.y + t2i;
    float e1r = va.x - t2r, e1i = va.y - t2i;
    float e2r = t1r + t3r,  e2i = t1i + t3i;
    float e3r = t1r - t3r,  e3i = t1i - t3i;
    const int i0 = 4 * j - 3 * k;
    d[SW2(i0)]          = make_float2(e0r + e2r, e0i + e2i);
    d[SW2(i0 + NS)]     = make_float2(e1r + e3i, e1i - e3r);
    d[SW2(i0 + 2*NS)]   = make_float2(e0r - e2r, e0i - e2i);
    d[SW2(i0 + 3*NS)]   = make_float2(e1r - e3i, e1i + e3r);
}

// ---------- setup: per-mel support + dense padded filter table filT[MAXW][80] ----------
__global__ __launch_bounds__(256) void k_ranges(const float* __restrict__ fil,
                                                int* __restrict__ rlo,
                                                float* __restrict__ filT)
{
    const int m    = blockIdx.x * 4 + (threadIdx.x >> 6);   // 20 blocks x 4 waves = 80 mels
    const int lane = threadIdx.x & 63;
    int lo = NBINS, hi = -1;
    for (int f = lane; f < NBINS; f += 64) {
        if (fil[f * NMEL + m] > 0.f) { lo = min(lo, f); hi = max(hi, f); }
    }
    #pragma unroll
    for (int o = 1; o < 64; o <<= 1) {
        lo = min(lo, __shfl_xor(lo, o, 64));
        hi = max(hi, __shfl_xor(hi, o, 64));
    }
    if (hi < 0) { lo = 0; hi = -1; }          // empty filter -> all zeros
    if (lane == 0) rlo[m] = lo;
    // fill padded dense column: filT[i][m], i in [0, MAXW)
    if (lane < MAXW) {
        int f = lo + lane;
        float v = (f <= hi && f < NBINS) ? fil[f * NMEL + m] : 0.f;
        filT[lane * NMEL + m] = v;
    }
}

// ---------- main: frames -> rFFT(512 via 256-pt complex) -> power -> dense-padded mel -> log ----------
__global__ __launch_bounds__(256) void k_frames(
    const float* __restrict__ raw, const float* __restrict__ mask,
    const float* __restrict__ filT, const float* __restrict__ win,
    const int* __restrict__ rlo,
    float* __restrict__ feats)
{
    __shared__ float2 A2[4][256];                            // FFT buffer A (8 KB)
    // B-side union: input staging, FFT ping-pong buffer B, and (after pass 4)
    // the per-wave power row. pow_[wv] aliases c2[wv] (stride 512 floats = 2048B);
    // each wave writes its own region with in-order LDS semantics, so no extra sync.
    __shared__ __align__(16) union {
        struct { float x[896]; float mk[896]; } in;          // staging (880 used), 7168B
        float2 c2[4][256];                                   // FFT ping-pong buffer B, 8192B
        float  pow_[4][512];                                 // power rows, alias of c2
    } U;
    __shared__ float s_filT[MAXW * NMEL];                    // 6.4 KB
    __shared__ int   s_rlo[NMEL];

    const int tid  = threadIdx.x;
    const int wv   = tid >> 6;
    const int lane = tid & 63;
    const int b    = blockIdx.y;
    const int fr0  = blockIdx.x * 4;
    const long sbase = (long)b * NSAMP + (long)fr0 * 160;
    const int  valid = NSAMP - fr0 * 160;

    // ---- stage filter table + rlo (L2-resident, coalesced) ----
    for (int i4 = tid; i4 < MAXW * NMEL / 4; i4 += 256) {
        *(float4*)&s_filT[i4 * 4] = *(const float4*)&filT[i4 * 4];
    }
    if (tid < NMEL) s_rlo[tid] = rlo[tid];

    // ---- stage 880 samples + mask into LDS (float4, scaled) ----
    for (int i4 = tid; i4 < 220; i4 += 256) {
        float4 xv = make_float4(0.f, 0.f, 0.f, 0.f);
        float4 mv = make_float4(0.f, 0.f, 0.f, 0.f);
        if (i4 * 4 + 4 <= valid) {
            xv = *(const float4*)(raw  + sbase + i4 * 4);
            mv = *(const float4*)(mask + sbase + i4 * 4);
        }
        xv.x *= 32768.f; xv.y *= 32768.f; xv.z *= 32768.f; xv.w *= 32768.f;
        *(float4*)&U.in.x[i4 * 4]  = xv;
        *(float4*)&U.in.mk[i4 * 4] = mv;
    }
    __syncthreads();

    // ---- per-frame mean (wave wv owns frame wv) ----
    float part = 0.f;
    for (int i = lane; i < 400; i += 64) part += U.in.x[wv * 160 + i];
    #pragma unroll
    for (int o = 1; o < 64; o <<= 1) part += __shfl_xor(part, o, 64);
    const float fmean = part * (1.0f / 400.0f);

    // ---- pack: z[n] = y(2n) + i*y(2n+1), lane handles n = 4l..4l+3 ----
    {
        const int l = lane;
        float ys[8];
        if (l < 50) {
            const float* xp = &U.in.x[wv * 160 + 8 * l];
            const float* mp = &U.in.mk[wv * 160 + 8 * l];
            float4 x0 = *(const float4*)xp,        x1 = *(const float4*)(xp + 4);
            float4 m0 = *(const float4*)mp,        m1 = *(const float4*)(mp + 4);
            float4 w0 = *(const float4*)(win + 8 * l), w1 = *(const float4*)(win + 8 * l + 4);
            float xm1 = (l > 0) ? xp[-1] : 0.f;
            float xs[8] = {x0.x, x0.y, x0.z, x0.w, x1.x, x1.y, x1.z, x1.w};
            float ms[8] = {m0.x, m0.y, m0.z, m0.w, m1.x, m1.y, m1.z, m1.w};
            float wf[8] = {w0.x, w0.y, w0.z, w0.w, w1.x, w1.y, w1.z, w1.w};
            #pragma unroll
            for (int e = 0; e < 8; ++e) {
                float xc = xs[e];
                float xprev = e ? xs[e - 1] : xm1;
                float y = (8 * l + e == 0) ? 0.03f * (xc - fmean)
                                           : (xc - 0.97f * xprev - 0.03f * fmean);
                ys[e] = y * wf[e] * ms[e];
            }
        } else {
            #pragma unroll
            for (int e = 0; e < 8; ++e) ys[e] = 0.f;
        }
        __syncthreads();   // all waves done reading U.in before U.c2 gets written (pass 1)
        #pragma unroll
        for (int d = 0; d < 4; ++d) {
            A2[wv][SW2(4 * l + d)] = make_float2(ys[2 * d], ys[2 * d + 1]);
        }
    }

    // ---- 256-pt complex FFT: 4 radix-4 Stockham passes (wave-private) ----
    r4pass2<1 >(&A2[wv][0],   &U.c2[wv][0], lane);
    r4pass2<4 >(&U.c2[wv][0], &A2[wv][0],   lane);
    r4pass2<16>(&A2[wv][0],   &U.c2[wv][0], lane);
    r4pass2<64>(&U.c2[wv][0], &A2[wv][0],   lane);
    // U.c2[wv] is now dead for this wave -> reuse as its power row U.pow_[wv].

    // ---- real-split unpack + power ----
    #pragma unroll
    for (int q = 0; q < 4; ++q) {
        int k  = lane + 64 * q;
        int a  = k & 255;
        int b2 = (256 - k) & 255;
        float2 za = A2[wv][SW2(a)];
        float2 zb = A2[wv][SW2(b2)];
        float Er  = 0.5f * (za.x + zb.x), Ei = 0.5f * (za.y - zb.y);
        float Or_ = 0.5f * (za.y + zb.y), Oi = 0.5f * (zb.x - za.x);
        float sk, ck;
        __sincosf((-PI_F / 256.0f) * (float)k, &sk, &ck);
        float Xr = Er + ck * Or_ - sk * Oi;
        float Xi = Ei + ck * Oi + sk * Or_;
        U.pow_[wv][k] = Xr * Xr + Xi * Xi;
    }
    if (lane == 0) {
        float2 z0 = A2[wv][SW2(0)];
        float Xr = z0.x - z0.y;
        U.pow_[wv][256] = Xr * Xr;
    }
    if (lane < 23) U.pow_[wv][257 + lane] = 0.f;   // zero pad so lo+MAXW-1 stays clean
    __syncthreads();

    // ---- dense padded mel (fixed MAXW iters, all-LDS) + log ----
    for (int p = tid; p < 4 * NMEL; p += 256) {
        int g = p / NMEL, m = p - NMEL * g;
        int fr = fr0 + g;
        if (fr >= NFRAMES) continue;
        int lo = s_rlo[m];
        float acc = 0.f;
        #pragma unroll
        for (int i = 0; i < MAXW; ++i) {
            acc = fmaf(U.pow_[g][lo + i], s_filT[i * NMEL + m], acc);
        }
        feats[((long)b * NFRAMES + fr) * NMEL + m] = __logf(fmaxf(acc, MEL_FLOOR));
    }
}

// ---------- stats stage 1: per (b, chunk) partial sums, coalesced float4 ----------
__global__ __launch_bounds__(256) void k_stats1(const float* __restrict__ feats,
                                                float* __restrict__ partials)
{
    const int b  = blockIdx.x;
    const int ch = blockIdx.y;
    const int t  = threadIdx.x;
    const int fr0 = (NFRAMES * ch) / SCHUNKS;
    const int fr1 = (NFRAMES * (ch + 1)) / SCHUNKS;

    float4 s  = make_float4(0.f, 0.f, 0.f, 0.f);
    float4 s2 = make_float4(0.f, 0.f, 0.f, 0.f);
    if (t < 240) {
        const int c = t % 20;
        const int r = t / 20;
        const float4* base = (const float4*)(feats + (long)b * NFRAMES * NMEL);
        for (int fr = fr0 + r; fr < fr1; fr += 12) {
            float4 v = base[(long)fr * 20 + c];
            s.x += v.x; s.y += v.y; s.z += v.z; s.w += v.w;
            s2.x += v.x * v.x; s2.y += v.y * v.y; s2.z += v.z * v.z; s2.w += v.w * v.w;
        }
    }
    __shared__ float4 ls[240], ls2[240];
    if (t < 240) { ls[t] = s; ls2[t] = s2; }
    __syncthreads();
    if (t < 20) {
        float4 a = ls[t], a2 = ls2[t];
        for (int r = 1; r < 12; ++r) {
            float4 u = ls[r * 20 + t], u2 = ls2[r * 20 + t];
            a.x += u.x; a.y += u.y; a.z += u.z; a.w += u.w;
            a2.x += u2.x; a2.y += u2.y; a2.z += u2.z; a2.w += u2.w;
        }
        float4* p = (float4*)(partials + (long)(b * SCHUNKS + ch) * 2 * NMEL);
        p[t]      = a;
        p[20 + t] = a2;
    }
}

// ---------- fused: fold chunks -> mean/rstd (prologue) + normalize + pad + mask ----------
__global__ __launch_bounds__(256) void k_out(const float* __restrict__ feats,
                                             const float* __restrict__ partials,
                                             float* __restrict__ out)
{
    const int b = blockIdx.y;
    const int t = threadIdx.x;
    __shared__ float sm[NMEL], sr[NMEL];

    if (t < NMEL) {
        const float* p = partials + (long)b * SCHUNKS * 2 * NMEL;
        float s = 0.f, s2 = 0.f;
        #pragma unroll 4
        for (int ch = 0; ch < SCHUNKS; ++ch) {
            s  += p[ch * 2 * NMEL + t];
            s2 += p[ch * 2 * NMEL + NMEL + t];
        }
        float mean = s * (1.0f / NFRAMES);
        float var  = (s2 - s * s * (1.0f / NFRAMES)) * (1.0f / (NFRAMES - 1));
        sm[t] = mean;
        sr[t] = rsqrtf(var + 1e-7f);
    }
    __syncthreads();

    const int tot4 = ROWS * COLS / 4;
    float* ob = out + (long)b * ROWS * COLS;
    for (int i = blockIdx.x * 256 + t; i < tot4; i += gridDim.x * 256) {
        int e = i * 4;
        int r = e / COLS, c = e % COLS;
        float4 o;
        if (r == ROWS - 1) {
            o = make_float4(1.f, 1.f, 1.f, 1.f);
        } else {
            int fr = 2 * r + (c >= NMEL);
            int m  = c % NMEL;
            const float4 f = *(const float4*)(feats + ((long)b * NFRAMES + fr) * NMEL + m);
            o.x = (f.x - sm[m])     * sr[m];
            o.y = (f.y - sm[m + 1]) * sr[m + 1];
            o.z = (f.z - sm[m + 2]) * sr[m + 2];
            o.w = (f.w - sm[m + 3]) * sr[m + 3];
        }
        *(float4*)(ob + e) = o;
    }

    if (blockIdx.x == 0) {
        float* omask = out + (long)BATCH * ROWS * COLS + (long)b * ROWS;
        for (int i = t; i < ROWS; i += 256) {
            omask[i] = (i == ROWS - 1) ? 0.0f : 1.0f;
        }
    }
}

extern "C" void kernel_launch(void* const* d_in, const int* in_sizes, int n_in,
                              void* d_out, int out_size, void* d_ws, size_t ws_size,
                              hipStream_t stream)
{
    const float* raw  = (const float*)d_in[0];
    const float* mask = (const float*)d_in[1];
    const float* fil  = (const float*)d_in[2];
    const float* win  = (const float*)d_in[3];
    float* out = (float*)d_out;

    float* feats    = (float*)d_ws;                               // 32*2998*80 f32
    float* partials = feats + (long)BATCH * NFRAMES * NMEL;       // 32*32*160 f32
    float* filT     = partials + (long)BATCH * SCHUNKS * 2 * NMEL;// 20*80 f32
    int*   rlo      = (int*)(filT + MAXW * NMEL);                 // 80 i32

    k_ranges<<<20, 256, 0, stream>>>(fil, rlo, filT);

    dim3 g1((NFRAMES + 3) / 4, BATCH);
    k_frames<<<g1, 256, 0, stream>>>(raw, mask, filT, win, rlo, feats);

    dim3 gs(BATCH, SCHUNKS);
    k_stats1<<<gs, 256, 0, stream>>>(feats, partials);

    dim3 go(16, BATCH);
    k_out<<<go, 256, 0, stream>>>(feats, partials, out);
}